// Round 2
// baseline (1924.409 us; speedup 1.0000x reference)
//
#include <hip/hip_runtime.h>
#include <cstdint>

// ---------------------------------------------------------------------------
// MHA_QAgent round 2: fp32 compute, bf16 intermediates, heavy weight folding.
//   Kq[h,b,c]   = own[b,:]·Mm[h,c,:] + bias2[h,c]      (q never materialized)
//   A_cat[b,:]  = [own(96) | wA 8x88 | wE 8x80]  bf16  (softmax-weighted feats)
//   gi          = A_cat @ UT^T + bias_gi               (xcat/Wo/V all folded)
//   gh          = prev_h @ W_hh^T + b_hh
// Workspace ~94 MB with gi aliasing the dead Kq region.
// ---------------------------------------------------------------------------

typedef unsigned short bf16_t;

__device__ inline float bf2f(bf16_t v) { return __uint_as_float(((unsigned)v) << 16); }
__device__ inline bf16_t f2bf(float x) {
    unsigned u = __float_as_uint(x);
    u += 0x7fffu + ((u >> 16) & 1u);          // RNE
    return (bf16_t)(u >> 16);
}

__device__ inline float4 loadA4(const float* p) { return *(const float4*)p; }
__device__ inline float4 loadA4(const bf16_t* p) {
    ushort4 u = *(const ushort4*)p;
    return make_float4(bf2f(u.x), bf2f(u.y), bf2f(u.z), bf2f(u.w));
}
__device__ inline void store4(float* p, float4 v) { *(float4*)p = v; }
__device__ inline void store4(bf16_t* p, float4 v) {
    ushort4 u; u.x = f2bf(v.x); u.y = f2bf(v.y); u.z = f2bf(v.z); u.w = f2bf(v.w);
    *(ushort4*)p = u;
}

// C[i,j] = sum_k A[i,k] * B(j,k) (+bias[j]).  BT=true: B row-major [N,K];
// BT=false: B row-major [K,N].  Per-z flat offsets on A/B/C/bias.
template <typename TA, typename TC, bool BT>
__global__ __launch_bounds__(256)
void gemm(const TA* __restrict__ A, int lda, int64_t azs,
          const float* __restrict__ Bm, int ldb, int64_t bzs,
          TC* __restrict__ C, int ldc, int64_t czs,
          const float* __restrict__ bias, int biaszs,
          int M, int N, int K)
{
    __shared__ float As[16][132];
    __shared__ float Bs[16][132];
    const int z = blockIdx.z;
    A += (int64_t)z * azs; Bm += (int64_t)z * bzs; C += (int64_t)z * czs;
    if (bias) bias += (int64_t)z * biaszs;
    const int m0 = blockIdx.x * 128, n0 = blockIdx.y * 128;
    const int tid = threadIdx.x, tx = tid & 15, ty = tid >> 4;
    float acc[8][8] = {};
    for (int k0 = 0; k0 < K; k0 += 16) {
#pragma unroll
        for (int l = 0; l < 2; ++l) {
            int f4 = tid + l * 256;
            {   // A tile: 128 rows x 16 k
                int row = f4 >> 2, kq = (f4 & 3) * 4, gk = k0 + kq, gr = m0 + row;
                float4 v = make_float4(0.f, 0.f, 0.f, 0.f);
                if (gr < M && gk < K) v = loadA4(A + (int64_t)gr * lda + gk);
                As[kq + 0][row] = v.x; As[kq + 1][row] = v.y;
                As[kq + 2][row] = v.z; As[kq + 3][row] = v.w;
            }
            if (BT) {
                int row = f4 >> 2, kq = (f4 & 3) * 4, gk = k0 + kq, gc = n0 + row;
                float4 v = make_float4(0.f, 0.f, 0.f, 0.f);
                if (gc < N && gk < K) v = *(const float4*)(Bm + (int64_t)gc * ldb + gk);
                Bs[kq + 0][row] = v.x; Bs[kq + 1][row] = v.y;
                Bs[kq + 2][row] = v.z; Bs[kq + 3][row] = v.w;
            } else {
                int kr = f4 >> 5, nc = (f4 & 31) * 4, gk = k0 + kr, gn = n0 + nc;
                float4 v = make_float4(0.f, 0.f, 0.f, 0.f);
                if (gk < K && gn < N) v = *(const float4*)(Bm + (int64_t)gk * ldb + gn);
                Bs[kr][nc + 0] = v.x; Bs[kr][nc + 1] = v.y;
                Bs[kr][nc + 2] = v.z; Bs[kr][nc + 3] = v.w;
            }
        }
        __syncthreads();
#pragma unroll
        for (int kk = 0; kk < 16; ++kk) {
            float a[8], b[8];
            *(float4*)&a[0] = *(const float4*)&As[kk][ty * 8 + 0];
            *(float4*)&a[4] = *(const float4*)&As[kk][ty * 8 + 4];
            *(float4*)&b[0] = *(const float4*)&Bs[kk][tx * 8 + 0];
            *(float4*)&b[4] = *(const float4*)&Bs[kk][tx * 8 + 4];
#pragma unroll
            for (int i = 0; i < 8; ++i)
#pragma unroll
                for (int j = 0; j < 8; ++j) acc[i][j] = fmaf(a[i], b[j], acc[i][j]);
        }
        __syncthreads();
    }
#pragma unroll
    for (int i = 0; i < 8; ++i) {
        int gr = m0 + ty * 8 + i;
        if (gr >= M) continue;
#pragma unroll
        for (int j4 = 0; j4 < 2; ++j4) {
            int gc = n0 + tx * 8 + j4 * 4;
            if (gc >= N) continue;                 // N % 4 == 0 for all uses
            float4 v;
            v.x = acc[i][j4 * 4 + 0] + (bias ? bias[gc + 0] : 0.f);
            v.y = acc[i][j4 * 4 + 1] + (bias ? bias[gc + 1] : 0.f);
            v.z = acc[i][j4 * 4 + 2] + (bias ? bias[gc + 2] : 0.f);
            v.w = acc[i][j4 * 4 + 3] + (bias ? bias[gc + 3] : 0.f);
            store4(C + (int64_t)gr * ldc + gc, v);
        }
    }
}

// fb[job][n] = bvec · W[:,n];  jobs: bqa,bqe,bkA,bvA,bkE,bvE
__global__ __launch_bounds__(64)
void bias_fuse(const float* __restrict__ b_own, const float* __restrict__ b_ally,
               const float* __restrict__ b_enemy,
               const float* __restrict__ Wq_a, const float* __restrict__ Wq_e,
               const float* __restrict__ Wk_a, const float* __restrict__ Wv_a,
               const float* __restrict__ Wk_e, const float* __restrict__ Wv_e,
               float* __restrict__ fb)
{
    int job = blockIdx.x;
    int n = blockIdx.y * 64 + threadIdx.x;
    const float* v; const float* W;
    switch (job) {
        case 0: v = b_own;   W = Wq_a; break;
        case 1: v = b_own;   W = Wq_e; break;
        case 2: v = b_ally;  W = Wk_a; break;
        case 3: v = b_ally;  W = Wv_a; break;
        case 4: v = b_enemy; W = Wk_e; break;
        default: v = b_enemy; W = Wv_e; break;
    }
    float s = 0.f;
    for (int h = 0; h < 512; ++h) s = fmaf(v[h], W[(int64_t)h * 512 + n], s);
    fb[job * 512 + n] = s;
}

// FkA row 88 <- bkA ; FkE row 80 <- bkE  (bias-row trick)
__global__ __launch_bounds__(256)
void fkbias_k(const float* __restrict__ fb, float* __restrict__ FkA, float* __restrict__ FkE)
{
    int i = blockIdx.x * 256 + threadIdx.x;
    if (i >= 512) return;
    FkA[88 * 512 + i] = fb[2 * 512 + i];
    FkE[80 * 512 + i] = fb[4 * 512 + i];
}

// WcatT[:,0:512] = W_ih[:,0:512]
__global__ __launch_bounds__(256)
void copy_wih_left(const float* __restrict__ W_ih, float* __restrict__ WcatT)
{
    int idx = blockIdx.x * 256 + threadIdx.x;   // 1536*128 float4
    if (idx >= 1536 * 128) return;
    int j = idx >> 7, k4 = (idx & 127) << 2;
    *(float4*)(WcatT + (int64_t)j * 1536 + k4) =
        *(const float4*)(W_ih + (int64_t)j * 1536 + k4);
}

// bias2[side][z][c] = bq_side[z*64+d] · Fk_side[c][z*64+d]
__global__ __launch_bounds__(256)
void bias2_k(const float* __restrict__ fb, const float* __restrict__ FkA,
             const float* __restrict__ FkE, float* __restrict__ b2a, float* __restrict__ b2e)
{
    int idx = blockIdx.x * 256 + threadIdx.x;   // 2*8*92
    if (idx >= 1472) return;
    int side = idx / 736, rem = idx - side * 736;
    int z = rem / 92, c = rem - z * 92;
    const float* W = side ? FkE : FkA;
    const float* bq = fb + side * 512;
    float s = 0.f;
    for (int d = 0; d < 64; ++d) s = fmaf(bq[z * 64 + d], W[(int64_t)c * 512 + z * 64 + d], s);
    (side ? b2e : b2a)[z * 92 + c] = s;
}

// bias_gi[j] = b_ih[j] + b_own·WcatT[j,0:512] + bvA·WcatT[j,512:1024] + bvE·WcatT[j,1024:1536]
__global__ __launch_bounds__(256)
void bias_gi_k(const float* __restrict__ b_ih, const float* __restrict__ b_own,
               const float* __restrict__ fb, const float* __restrict__ WcatT,
               float* __restrict__ bias_gi)
{
    int j = blockIdx.x * 256 + threadIdx.x;
    if (j >= 1536) return;
    const float* row = WcatT + (int64_t)j * 1536;
    float s = b_ih[j];
    for (int k = 0; k < 512; ++k) {
        s = fmaf(b_own[k],        row[k],        s);
        s = fmaf(fb[3 * 512 + k], row[512 + k],  s);
        s = fmaf(fb[5 * 512 + k], row[1024 + k], s);
    }
    bias_gi[j] = s;
}

// scores via Kq, mask, softmax, feature re-weighting -> A_cat (bf16).
// Kq row stride 92; col DF holds the fused k-bias·q term.
template <int NENT, int DF, int OFF, bool COPYOWN>
__global__ __launch_bounds__(128)
void attn_mid(const float* __restrict__ ent, const float* __restrict__ Kq,
              const float* __restrict__ own, bf16_t* __restrict__ acat, int B)
{
    const int b = blockIdx.x, tid = threadIdx.x;
    __shared__ float sent[NENT * DF];
    __shared__ float sKq[8 * (DF + 1)];
    __shared__ float ssc[8][NENT];
    __shared__ int smask[NENT];

    const float* eb = ent + (int64_t)b * NENT * DF;
    for (int i = tid; i < NENT * DF; i += 128) sent[i] = eb[i];
    for (int i = tid; i < 8 * (DF + 1); i += 128) {
        int h = i / (DF + 1), c = i - h * (DF + 1);
        sKq[i] = Kq[((int64_t)h * B + b) * 92 + c];
    }
    __syncthreads();
    if (tid < NENT) {
        int any = 0;
        for (int c = 0; c < DF; ++c) any |= (sent[tid * DF + c] != 0.f);
        smask[tid] = any;
    }
    __syncthreads();
    for (int t = tid; t < 8 * NENT; t += 128) {
        int h = t / NENT, i = t - h * NENT;
        const float* kqh = &sKq[h * (DF + 1)];
        float s = 0.f;
        for (int c = 0; c < DF; ++c) s = fmaf(sent[i * DF + c], kqh[c], s);
        s = (s + kqh[DF]) * 0.125f;                 // / sqrt(64)
        if (!smask[i]) s = -1e9f;
        ssc[h][i] = s;
    }
    __syncthreads();
    if (tid < 8) {
        float m = -INFINITY;
        for (int i = 0; i < NENT; ++i) m = fmaxf(m, ssc[tid][i]);
        float e[NENT], sum = 0.f;
        for (int i = 0; i < NENT; ++i) { e[i] = expf(ssc[tid][i] - m); sum += e[i]; }
        float inv = 1.f / sum;
        for (int i = 0; i < NENT; ++i) ssc[tid][i] = e[i] * inv;
    }
    __syncthreads();
    bf16_t* arow = acat + (int64_t)b * 1440;
    if (COPYOWN) {
        const float* ob = own + (int64_t)b * 96;
        for (int c = tid; c < 96; c += 128) arow[c] = f2bf(ob[c]);
    }
    for (int t = tid; t < 8 * DF; t += 128) {
        int h = t / DF, c = t - h * DF;
        float s = 0.f;
        for (int i = 0; i < NENT; ++i) s = fmaf(ssc[h][i], sent[i * DF + c], s);
        arow[OFF + h * DF + c] = f2bf(s);
    }
}

// GRU combine + 512->22 head
__global__ __launch_bounds__(256)
void gru_final(const bf16_t* __restrict__ gi, const bf16_t* __restrict__ gh,
               const float* __restrict__ ph, const float* __restrict__ Wq,
               const float* __restrict__ bq, float* __restrict__ out, int B)
{
    const int b = blockIdx.x, tid = threadIdx.x;
    __shared__ float sh[512];
    const bf16_t* gib = gi + (int64_t)b * 1536;
    const bf16_t* ghb = gh + (int64_t)b * 1536;
    const float* phb = ph + (int64_t)b * 512;
    for (int n = tid; n < 512; n += 256) {
        float r = 1.f / (1.f + expf(-(bf2f(gib[n]) + bf2f(ghb[n]))));
        float z = 1.f / (1.f + expf(-(bf2f(gib[512 + n]) + bf2f(ghb[512 + n]))));
        float nn = tanhf(bf2f(gib[1024 + n]) + r * bf2f(ghb[1024 + n]));
        sh[n] = (1.f - z) * nn + z * phb[n];
    }
    __syncthreads();
    if (tid < 176) {                        // 22 outputs x 8 lanes
        int j = tid >> 3, l = tid & 7;
        float s = 0.f;
        for (int k = l; k < 512; k += 8) s = fmaf(sh[k], Wq[k * 22 + j], s);
        s += __shfl_down(s, 4, 64);
        s += __shfl_down(s, 2, 64);
        s += __shfl_down(s, 1, 64);
        if (l == 0) out[(int64_t)b * 22 + j] = s + bq[j];
    }
}

extern "C" void kernel_launch(void* const* d_in, const int* in_sizes, int n_in,
                              void* d_out, int out_size, void* d_ws, size_t ws_size,
                              hipStream_t stream)
{
    const float* own    = (const float*)d_in[0];
    const float* ally   = (const float*)d_in[1];
    const float* enemy  = (const float*)d_in[2];
    const float* prev_h = (const float*)d_in[3];
    const float* W_own  = (const float*)d_in[4];
    const float* b_own  = (const float*)d_in[5];
    const float* W_ally = (const float*)d_in[6];
    // d_in[7] = b_ally, d_in[9] = b_enemy  (used via bias_fuse only)
    const float* b_ally = (const float*)d_in[7];
    const float* W_enemy= (const float*)d_in[8];
    const float* b_enemy= (const float*)d_in[9];
    const float* Wq_a   = (const float*)d_in[10];
    const float* Wk_a   = (const float*)d_in[11];
    const float* Wv_a   = (const float*)d_in[12];
    const float* Wo_a   = (const float*)d_in[13];
    const float* Wq_e   = (const float*)d_in[14];
    const float* Wk_e   = (const float*)d_in[15];
    const float* Wv_e   = (const float*)d_in[16];
    const float* Wo_e   = (const float*)d_in[17];
    const float* W_ih   = (const float*)d_in[18];
    const float* W_hh   = (const float*)d_in[19];
    const float* b_ih   = (const float*)d_in[20];
    const float* b_hh   = (const float*)d_in[21];
    const float* W_q    = (const float*)d_in[22];
    const float* b_q    = (const float*)d_in[23];
    float* outq = (float*)d_out;
    (void)n_in; (void)out_size;

    const int B = in_sizes[0] / 96;   // 8192

    float* w = (float*)d_ws;
    size_t o = 0;
    auto alloc = [&](size_t n) { float* p = w + o; o += n; return p; };
    float* Fq_a   = alloc(96 * 512);
    float* Fq_e   = alloc(96 * 512);
    float* FkA    = alloc(92 * 512);     // rows 0..87 data, row 88 = bkA
    float* FkE    = alloc(92 * 512);     // rows 0..79 data, row 80 = bkE
    float* FvA    = alloc(88 * 512);
    float* FvE    = alloc(80 * 512);
    float* Mm_a   = alloc(8 * 92 * 96);
    float* Mm_e   = alloc(8 * 92 * 96);
    float* b2a    = alloc(8 * 92);       // 736
    float* b2e    = alloc(8 * 92);
    float* fb     = alloc(6 * 512);
    float* bias_gi= alloc(1536);
    float* WcatT  = alloc(1536 * 1536);
    float* UT     = alloc(1536 * 1440);
    bf16_t* A_cat = (bf16_t*)alloc((size_t)B * 1440 / 2);      // bf16
    float* KqReg  = alloc((size_t)B * 1536 / 2);               // max(Kq fp32, gi bf16)
    bf16_t* gh    = (bf16_t*)alloc((size_t)B * 1536 / 2);      // bf16
    float* Kq     = KqReg;                                     // 8*B*92 fp32 fits
    bf16_t* gi    = (bf16_t*)KqReg;                            // aliases dead Kq

    if (ws_size < o * sizeof(float)) return;   // clean fail (absmax), not a fault

    auto GNT = [&](const float* A, int lda, int64_t az, const float* Bm, int ldb, int64_t bz,
                   float* C, int ldc, int64_t cz, const float* bias, int bzo,
                   int M, int N, int K, int Z = 1) {
        dim3 g((M + 127) / 128, (N + 127) / 128, Z);
        hipLaunchKernelGGL((gemm<float, float, true>), g, dim3(256), 0, stream,
                           A, lda, az, Bm, ldb, bz, C, ldc, cz, bias, bzo, M, N, K);
    };
    auto GNN = [&](const float* A, int lda, const float* Bm, int ldb,
                   float* C, int ldc, int M, int N, int K) {
        dim3 g((M + 127) / 128, (N + 127) / 128, 1);
        hipLaunchKernelGGL((gemm<float, float, false>), g, dim3(256), 0, stream,
                           A, lda, 0, Bm, ldb, 0, C, ldc, 0, (const float*)nullptr, 0, M, N, K);
    };

    // ---------------- weight precompute ----------------
    hipLaunchKernelGGL(bias_fuse, dim3(6, 8), dim3(64), 0, stream,
                       b_own, b_ally, b_enemy, Wq_a, Wq_e, Wk_a, Wv_a, Wk_e, Wv_e, fb);
    GNN(W_own,   512, Wq_a, 512, Fq_a, 512, 96, 512, 512);    // Fq = W_own@Wq
    GNN(W_own,   512, Wq_e, 512, Fq_e, 512, 96, 512, 512);
    GNN(W_ally,  512, Wk_a, 512, FkA,  512, 88, 512, 512);    // Fk = W_ent@Wk
    GNN(W_enemy, 512, Wk_e, 512, FkE,  512, 80, 512, 512);
    GNN(W_ally,  512, Wv_a, 512, FvA,  512, 88, 512, 512);    // Fv = W_ent@Wv
    GNN(W_enemy, 512, Wv_e, 512, FvE,  512, 80, 512, 512);
    hipLaunchKernelGGL(fkbias_k, dim3(2), dim3(256), 0, stream, fb, FkA, FkE);

    hipLaunchKernelGGL(copy_wih_left, dim3(768), dim3(256), 0, stream, W_ih, WcatT);
    GNT(W_ih + 512,  1536, 0, Wo_a, 512, 0, WcatT + 512,  1536, 0, nullptr, 0, 1536, 512, 512);
    GNT(W_ih + 1024, 1536, 0, Wo_e, 512, 0, WcatT + 1024, 1536, 0, nullptr, 0, 1536, 512, 512);

    GNT(WcatT, 1536, 0, W_own, 512, 0, UT, 1440, 0, nullptr, 0, 1536, 96, 512);          // UT[:,0:96]
    GNT(WcatT + 512,  1536, 64, FvA, 512, 64, UT + 96,  1440, 88, nullptr, 0, 1536, 88, 64, 8);
    GNT(WcatT + 1024, 1536, 64, FvE, 512, 64, UT + 800, 1440, 80, nullptr, 0, 1536, 80, 64, 8);

    GNT(FkA, 512, 64, Fq_a, 512, 64, Mm_a, 96, 92 * 96, nullptr, 0, 92, 96, 64, 8);      // Mm[h,c,cc]
    GNT(FkE, 512, 64, Fq_e, 512, 64, Mm_e, 96, 92 * 96, nullptr, 0, 92, 96, 64, 8);
    hipLaunchKernelGGL(bias2_k, dim3(6), dim3(256), 0, stream, fb, FkA, FkE, b2a, b2e);
    hipLaunchKernelGGL(bias_gi_k, dim3(6), dim3(256), 0, stream, b_ih, b_own, fb, WcatT, bias_gi);

    // ---------------- main pipeline ----------------
    GNT(own, 96, 0, Mm_a, 96, 92 * 96, Kq, 92, (int64_t)B * 92, b2a, 92, B, 92, 96, 8);  // Kq ally
    hipLaunchKernelGGL((attn_mid<15, 88, 96, true>), dim3(B), dim3(128), 0, stream,
                       ally, Kq, own, A_cat, B);
    GNT(own, 96, 0, Mm_e, 96, 92 * 96, Kq, 92, (int64_t)B * 92, b2e, 92, B, 92, 96, 8);  // Kq enemy
    hipLaunchKernelGGL((attn_mid<16, 80, 800, false>), dim3(B), dim3(128), 0, stream,
                       enemy, Kq, own, A_cat, B);

    {   // gi = A_cat @ UT^T + bias_gi   (bf16 A, bf16 C)
        dim3 g((B + 127) / 128, (1536 + 127) / 128, 1);
        hipLaunchKernelGGL((gemm<bf16_t, bf16_t, true>), g, dim3(256), 0, stream,
                           (const bf16_t*)A_cat, 1440, (int64_t)0, UT, 1440, (int64_t)0,
                           gi, 1536, (int64_t)0, bias_gi, 0, B, 1536, 1440);
    }
    {   // gh = prev_h @ W_hh^T + b_hh   (fp32 A, bf16 C)
        dim3 g((B + 127) / 128, (1536 + 127) / 128, 1);
        hipLaunchKernelGGL((gemm<float, bf16_t, true>), g, dim3(256), 0, stream,
                           prev_h, 512, (int64_t)0, W_hh, 512, (int64_t)0,
                           gh, 1536, (int64_t)0, b_hh, 0, B, 1536, 512);
    }
    hipLaunchKernelGGL(gru_final, dim3(B), dim3(256), 0, stream,
                       gi, gh, prev_h, W_q, b_q, outq, B);
}

// Round 3
// 774.984 us; speedup vs baseline: 2.4832x; 2.4832x over previous
//
#include <hip/hip_runtime.h>
#include <cstdint>

// ---------------------------------------------------------------------------
// MHA_QAgent round 3: MFMA bf16 for the two big GEMMs (gi, gh) + batched
// precompute (8-job multi-GEMM, Z=16 Kq GEMM).  ~91 MB workspace.
//   Kq[h,b,c]   = own[b,:]·Mm[h,c,:] + bias2[h,c]      (bf16, 16 slices)
//   A_cat[b,:]  = [own(96) | wA 8x88 | wE 8x80]  bf16
//   gi          = A_cat @ UT^T + bias_gi   (MFMA 16x16x32 bf16, K=1440)
//   gh          = prev_h @ W_hh^T + b_hh   (MFMA, K=512)
// ---------------------------------------------------------------------------

typedef unsigned short bf16_t;
typedef __attribute__((ext_vector_type(8))) short bf16x8;
typedef __attribute__((ext_vector_type(4))) float f32x4;

__device__ inline float bf2f(bf16_t v) { return __uint_as_float(((unsigned)v) << 16); }
__device__ inline bf16_t f2bf(float x) {
    unsigned u = __float_as_uint(x);
    u += 0x7fffu + ((u >> 16) & 1u);          // RNE
    return (bf16_t)(u >> 16);
}

__device__ inline float4 loadA4(const float* p) { return *(const float4*)p; }
__device__ inline void store4(float* p, float4 v) { *(float4*)p = v; }
__device__ inline void store4(bf16_t* p, float4 v) {
    ushort4 u; u.x = f2bf(v.x); u.y = f2bf(v.y); u.z = f2bf(v.z); u.w = f2bf(v.w);
    *(ushort4*)p = u;
}

__device__ inline void gload16(const bf16_t* g, bf16_t* l) {
    __builtin_amdgcn_global_load_lds(
        (const __attribute__((address_space(1))) void*)g,
        (__attribute__((address_space(3))) void*)l, 16, 0, 0);
}

// ---------------- fp32 tiled GEMM (precompute paths) ----------------
// C[i,j] = sum_k A[i,k] * B[j,k] (+bias[j]);  B row-major [N,K].
template <typename TC>
__global__ __launch_bounds__(256)
void gemm_nt(const float* __restrict__ A, int lda, int64_t azs,
             const float* __restrict__ Bm, int ldb, int64_t bzs,
             TC* __restrict__ C, int ldc, int64_t czs,
             const float* __restrict__ bias, int biaszs,
             int M, int N, int K)
{
    __shared__ float As[16][132];
    __shared__ float Bs[16][132];
    const int z = blockIdx.z;
    A += (int64_t)z * azs; Bm += (int64_t)z * bzs; C += (int64_t)z * czs;
    if (bias) bias += (int64_t)z * biaszs;
    const int m0 = blockIdx.x * 128, n0 = blockIdx.y * 128;
    const int tid = threadIdx.x, tx = tid & 15, ty = tid >> 4;
    float acc[8][8] = {};
    for (int k0 = 0; k0 < K; k0 += 16) {
#pragma unroll
        for (int l = 0; l < 2; ++l) {
            int f4 = tid + l * 256;
            int row = f4 >> 2, kq = (f4 & 3) * 4, gk = k0 + kq;
            {   int gr = m0 + row;
                float4 v = make_float4(0.f, 0.f, 0.f, 0.f);
                if (gr < M && gk < K) v = loadA4(A + (int64_t)gr * lda + gk);
                As[kq + 0][row] = v.x; As[kq + 1][row] = v.y;
                As[kq + 2][row] = v.z; As[kq + 3][row] = v.w;
            }
            {   int gc = n0 + row;
                float4 v = make_float4(0.f, 0.f, 0.f, 0.f);
                if (gc < N && gk < K) v = *(const float4*)(Bm + (int64_t)gc * ldb + gk);
                Bs[kq + 0][row] = v.x; Bs[kq + 1][row] = v.y;
                Bs[kq + 2][row] = v.z; Bs[kq + 3][row] = v.w;
            }
        }
        __syncthreads();
#pragma unroll
        for (int kk = 0; kk < 16; ++kk) {
            float a[8], b[8];
            *(float4*)&a[0] = *(const float4*)&As[kk][ty * 8 + 0];
            *(float4*)&a[4] = *(const float4*)&As[kk][ty * 8 + 4];
            *(float4*)&b[0] = *(const float4*)&Bs[kk][tx * 8 + 0];
            *(float4*)&b[4] = *(const float4*)&Bs[kk][tx * 8 + 4];
#pragma unroll
            for (int i = 0; i < 8; ++i)
#pragma unroll
                for (int j = 0; j < 8; ++j) acc[i][j] = fmaf(a[i], b[j], acc[i][j]);
        }
        __syncthreads();
    }
#pragma unroll
    for (int i = 0; i < 8; ++i) {
        int gr = m0 + ty * 8 + i;
        if (gr >= M) continue;
#pragma unroll
        for (int j4 = 0; j4 < 2; ++j4) {
            int gc = n0 + tx * 8 + j4 * 4;
            if (gc >= N) continue;                 // N % 4 == 0 for all uses
            float4 v;
            v.x = acc[i][j4 * 4 + 0] + (bias ? bias[gc + 0] : 0.f);
            v.y = acc[i][j4 * 4 + 1] + (bias ? bias[gc + 1] : 0.f);
            v.z = acc[i][j4 * 4 + 2] + (bias ? bias[gc + 2] : 0.f);
            v.w = acc[i][j4 * 4 + 3] + (bias ? bias[gc + 3] : 0.f);
            store4(C + (int64_t)gr * ldc + gc, v);
        }
    }
}

// 8 heterogeneous fp32 GEMMs in one launch (z = job).  bt: B [N,K] vs [K,N].
struct GemmJob { const float* A; const float* B; float* C; int M, lda, ldb, ldc, bt; };
struct GemmJobs8 { GemmJob j[8]; };

__global__ __launch_bounds__(256)
void gemm_multi(GemmJobs8 T, int N, int K)
{
    GemmJob jb = T.j[blockIdx.z];
    const int m0 = blockIdx.x * 128, n0 = blockIdx.y * 128;
    if (m0 >= jb.M) return;
    __shared__ float As[16][132];
    __shared__ float Bs[16][132];
    const int tid = threadIdx.x, tx = tid & 15, ty = tid >> 4;
    float acc[8][8] = {};
    for (int k0 = 0; k0 < K; k0 += 16) {
#pragma unroll
        for (int l = 0; l < 2; ++l) {
            int f4 = tid + l * 256;
            {   int row = f4 >> 2, kq = (f4 & 3) * 4, gk = k0 + kq, gr = m0 + row;
                float4 v = make_float4(0.f, 0.f, 0.f, 0.f);
                if (gr < jb.M) v = loadA4(jb.A + (int64_t)gr * jb.lda + gk);
                As[kq + 0][row] = v.x; As[kq + 1][row] = v.y;
                As[kq + 2][row] = v.z; As[kq + 3][row] = v.w;
            }
            if (jb.bt) {
                int row = f4 >> 2, kq = (f4 & 3) * 4, gk = k0 + kq, gc = n0 + row;
                float4 v = *(const float4*)(jb.B + (int64_t)gc * jb.ldb + gk);
                Bs[kq + 0][row] = v.x; Bs[kq + 1][row] = v.y;
                Bs[kq + 2][row] = v.z; Bs[kq + 3][row] = v.w;
            } else {
                int kr = f4 >> 5, nc = (f4 & 31) * 4, gk = k0 + kr, gn = n0 + nc;
                float4 v = *(const float4*)(jb.B + (int64_t)gk * jb.ldb + gn);
                Bs[kr][nc + 0] = v.x; Bs[kr][nc + 1] = v.y;
                Bs[kr][nc + 2] = v.z; Bs[kr][nc + 3] = v.w;
            }
        }
        __syncthreads();
#pragma unroll
        for (int kk = 0; kk < 16; ++kk) {
            float a[8], b[8];
            *(float4*)&a[0] = *(const float4*)&As[kk][ty * 8 + 0];
            *(float4*)&a[4] = *(const float4*)&As[kk][ty * 8 + 4];
            *(float4*)&b[0] = *(const float4*)&Bs[kk][tx * 8 + 0];
            *(float4*)&b[4] = *(const float4*)&Bs[kk][tx * 8 + 4];
#pragma unroll
            for (int i = 0; i < 8; ++i)
#pragma unroll
                for (int j = 0; j < 8; ++j) acc[i][j] = fmaf(a[i], b[j], acc[i][j]);
        }
        __syncthreads();
    }
#pragma unroll
    for (int i = 0; i < 8; ++i) {
        int gr = m0 + ty * 8 + i;
        if (gr >= jb.M) continue;
#pragma unroll
        for (int j4 = 0; j4 < 2; ++j4) {
            int gc = n0 + tx * 8 + j4 * 4;
            float4 v = make_float4(acc[i][j4 * 4 + 0], acc[i][j4 * 4 + 1],
                                   acc[i][j4 * 4 + 2], acc[i][j4 * 4 + 3]);
            store4(jb.C + (int64_t)gr * jb.ldc + gc, v);
        }
    }
}

// ---------------- MFMA bf16 NT GEMM: C[M,N] = A[M,K] @ B[N,K]^T + bias ----
// M%128==0, N%128==0, K%32==0.  256 threads = 4 waves (2x2), wave tile 64x64.
__global__ __launch_bounds__(256)
void mfma_nt(const bf16_t* __restrict__ A, int lda,
             const bf16_t* __restrict__ Bm, int ldb,
             bf16_t* __restrict__ C, int ldc,
             const float* __restrict__ bias, int K)
{
    __shared__ bf16_t As[128][32];
    __shared__ bf16_t Bs[128][32];
    const int tid = threadIdx.x;
    const int wv = tid >> 6, lane = tid & 63;
    const int fr = lane & 15, fq = lane >> 4;
    const int m0 = blockIdx.x * 128, n0 = blockIdx.y * 128;
    const int wm = (wv & 1) * 64, wn = (wv >> 1) * 64;

    f32x4 acc[4][4] = {};

    const bf16_t* gA = A + (int64_t)(m0 + (tid >> 2)) * lda + (tid & 3) * 8;
    const bf16_t* gB = Bm + (int64_t)(n0 + (tid >> 2)) * ldb + (tid & 3) * 8;
    bf16_t* lA0 = &As[wv * 16][0];
    bf16_t* lA1 = &As[64 + wv * 16][0];
    bf16_t* lB0 = &Bs[wv * 16][0];
    bf16_t* lB1 = &Bs[64 + wv * 16][0];
    const int64_t a64 = (int64_t)64 * lda, b64 = (int64_t)64 * ldb;

    for (int k0 = 0; k0 < K; k0 += 32) {
        gload16(gA, lA0);
        gload16(gA + a64, lA1);
        gload16(gB, lB0);
        gload16(gB + b64, lB1);
        gA += 32; gB += 32;
        __syncthreads();           // drains vmcnt before barrier (compiler)
        bf16x8 aF[4], bF[4];
#pragma unroll
        for (int i = 0; i < 4; ++i) aF[i] = *(const bf16x8*)&As[wm + i * 16 + fr][fq * 8];
#pragma unroll
        for (int j = 0; j < 4; ++j) bF[j] = *(const bf16x8*)&Bs[wn + j * 16 + fr][fq * 8];
#pragma unroll
        for (int i = 0; i < 4; ++i)
#pragma unroll
            for (int j = 0; j < 4; ++j)
                acc[i][j] = __builtin_amdgcn_mfma_f32_16x16x32_bf16(aF[i], bF[j], acc[i][j], 0, 0, 0);
        __syncthreads();
    }
#pragma unroll
    for (int j = 0; j < 4; ++j) {
        const int col = n0 + wn + j * 16 + fr;
        const float bv = bias[col];
#pragma unroll
        for (int i = 0; i < 4; ++i) {
            const int row = m0 + wm + i * 16 + fq * 4;
#pragma unroll
            for (int r = 0; r < 4; ++r)
                C[(int64_t)(row + r) * ldc + col] = f2bf(acc[i][j][r] + bv);
        }
    }
}

// ---------------- small helper kernels ----------------
__global__ __launch_bounds__(256)
void f2bf_copy(const float* __restrict__ in, bf16_t* __restrict__ out, int n4)
{
    int i = blockIdx.x * 256 + threadIdx.x;
    if (i >= n4) return;
    float4 v = ((const float4*)in)[i];
    ushort4 u; u.x = f2bf(v.x); u.y = f2bf(v.y); u.z = f2bf(v.z); u.w = f2bf(v.w);
    ((ushort4*)out)[i] = u;
}

// fb[job][n] = bvec · W[:,n];  jobs: bqa,bqe,bkA,bvA,bkE,bvE
__global__ __launch_bounds__(64)
void bias_fuse(const float* __restrict__ b_own, const float* __restrict__ b_ally,
               const float* __restrict__ b_enemy,
               const float* __restrict__ Wq_a, const float* __restrict__ Wq_e,
               const float* __restrict__ Wk_a, const float* __restrict__ Wv_a,
               const float* __restrict__ Wk_e, const float* __restrict__ Wv_e,
               float* __restrict__ fb)
{
    int job = blockIdx.x;
    int n = blockIdx.y * 64 + threadIdx.x;
    const float* v; const float* W;
    switch (job) {
        case 0: v = b_own;   W = Wq_a; break;
        case 1: v = b_own;   W = Wq_e; break;
        case 2: v = b_ally;  W = Wk_a; break;
        case 3: v = b_ally;  W = Wv_a; break;
        case 4: v = b_enemy; W = Wk_e; break;
        default: v = b_enemy; W = Wv_e; break;
    }
    float s = 0.f;
    for (int h = 0; h < 512; ++h) s = fmaf(v[h], W[(int64_t)h * 512 + n], s);
    fb[job * 512 + n] = s;
}

// FkA row 88 <- bkA ; FkE row 80 <- bkE  (bias-row trick)
__global__ __launch_bounds__(256)
void fkbias_k(const float* __restrict__ fb, float* __restrict__ FkA, float* __restrict__ FkE)
{
    int i = blockIdx.x * 256 + threadIdx.x;
    if (i >= 512) return;
    FkA[88 * 512 + i] = fb[2 * 512 + i];
    FkE[80 * 512 + i] = fb[4 * 512 + i];
}

// WcatT[:,0:512] = W_ih[:,0:512]
__global__ __launch_bounds__(256)
void copy_wih_left(const float* __restrict__ W_ih, float* __restrict__ WcatT)
{
    int idx = blockIdx.x * 256 + threadIdx.x;   // 1536*128 float4
    if (idx >= 1536 * 128) return;
    int j = idx >> 7, k4 = (idx & 127) << 2;
    *(float4*)(WcatT + (int64_t)j * 1536 + k4) =
        *(const float4*)(W_ih + (int64_t)j * 1536 + k4);
}

// bias2[side][z][c] = bq_side[z*64+d] · Fk_side[c][z*64+d]
__global__ __launch_bounds__(256)
void bias2_k(const float* __restrict__ fb, const float* __restrict__ FkA,
             const float* __restrict__ FkE, float* __restrict__ b2a, float* __restrict__ b2e)
{
    int idx = blockIdx.x * 256 + threadIdx.x;   // 2*8*92
    if (idx >= 1472) return;
    int side = idx / 736, rem = idx - side * 736;
    int z = rem / 92, c = rem - z * 92;
    const float* W = side ? FkE : FkA;
    const float* bq = fb + side * 512;
    float s = 0.f;
    for (int d = 0; d < 64; ++d) s = fmaf(bq[z * 64 + d], W[(int64_t)c * 512 + z * 64 + d], s);
    (side ? b2e : b2a)[z * 92 + c] = s;
}

// bias_gi[j] = b_ih[j] + b_own·WcatT[j,0:512] + bvA·WcatT[j,512:1024] + bvE·WcatT[j,1024:1536]
__global__ __launch_bounds__(256)
void bias_gi_k(const float* __restrict__ b_ih, const float* __restrict__ b_own,
               const float* __restrict__ fb, const float* __restrict__ WcatT,
               float* __restrict__ bias_gi)
{
    int j = blockIdx.x * 256 + threadIdx.x;
    if (j >= 1536) return;
    const float* row = WcatT + (int64_t)j * 1536;
    float s = b_ih[j];
    for (int k = 0; k < 512; ++k) {
        s = fmaf(b_own[k],        row[k],        s);
        s = fmaf(fb[3 * 512 + k], row[512 + k],  s);
        s = fmaf(fb[5 * 512 + k], row[1024 + k], s);
    }
    bias_gi[j] = s;
}

// scores via Kq (bf16), mask, softmax, feature re-weighting -> A_cat (bf16).
// Kq row stride 92; col DF holds the fused k-bias·q term.
template <int NENT, int DF, int OFF, bool COPYOWN>
__global__ __launch_bounds__(128)
void attn_mid(const float* __restrict__ ent, const bf16_t* __restrict__ Kq,
              const float* __restrict__ own, bf16_t* __restrict__ acat, int B)
{
    const int b = blockIdx.x, tid = threadIdx.x;
    __shared__ float sent[NENT * DF];
    __shared__ float sKq[8 * (DF + 1)];
    __shared__ float ssc[8][NENT];
    __shared__ int smask[NENT];

    const float* eb = ent + (int64_t)b * NENT * DF;
    for (int i = tid; i < NENT * DF; i += 128) sent[i] = eb[i];
    for (int i = tid; i < 8 * (DF + 1); i += 128) {
        int h = i / (DF + 1), c = i - h * (DF + 1);
        sKq[i] = bf2f(Kq[((int64_t)h * B + b) * 92 + c]);
    }
    __syncthreads();
    if (tid < NENT) {
        int any = 0;
        for (int c = 0; c < DF; ++c) any |= (sent[tid * DF + c] != 0.f);
        smask[tid] = any;
    }
    __syncthreads();
    for (int t = tid; t < 8 * NENT; t += 128) {
        int h = t / NENT, i = t - h * NENT;
        const float* kqh = &sKq[h * (DF + 1)];
        float s = 0.f;
        for (int c = 0; c < DF; ++c) s = fmaf(sent[i * DF + c], kqh[c], s);
        s = (s + kqh[DF]) * 0.125f;                 // / sqrt(64)
        if (!smask[i]) s = -1e9f;
        ssc[h][i] = s;
    }
    __syncthreads();
    if (tid < 8) {
        float m = -INFINITY;
        for (int i = 0; i < NENT; ++i) m = fmaxf(m, ssc[tid][i]);
        float e[NENT], sum = 0.f;
        for (int i = 0; i < NENT; ++i) { e[i] = expf(ssc[tid][i] - m); sum += e[i]; }
        float inv = 1.f / sum;
        for (int i = 0; i < NENT; ++i) ssc[tid][i] = e[i] * inv;
    }
    __syncthreads();
    bf16_t* arow = acat + (int64_t)b * 1440;
    if (COPYOWN) {
        const float* ob = own + (int64_t)b * 96;
        for (int c = tid; c < 96; c += 128) arow[c] = f2bf(ob[c]);
    }
    for (int t = tid; t < 8 * DF; t += 128) {
        int h = t / DF, c = t - h * DF;
        float s = 0.f;
        for (int i = 0; i < NENT; ++i) s = fmaf(ssc[h][i], sent[i * DF + c], s);
        arow[OFF + h * DF + c] = f2bf(s);
    }
}

// GRU combine + 512->22 head
__global__ __launch_bounds__(256)
void gru_final(const bf16_t* __restrict__ gi, const bf16_t* __restrict__ gh,
               const float* __restrict__ ph, const float* __restrict__ Wq,
               const float* __restrict__ bq, float* __restrict__ out, int B)
{
    const int b = blockIdx.x, tid = threadIdx.x;
    __shared__ float sh[512];
    const bf16_t* gib = gi + (int64_t)b * 1536;
    const bf16_t* ghb = gh + (int64_t)b * 1536;
    const float* phb = ph + (int64_t)b * 512;
    for (int n = tid; n < 512; n += 256) {
        float r = 1.f / (1.f + expf(-(bf2f(gib[n]) + bf2f(ghb[n]))));
        float z = 1.f / (1.f + expf(-(bf2f(gib[512 + n]) + bf2f(ghb[512 + n]))));
        float nn = tanhf(bf2f(gib[1024 + n]) + r * bf2f(ghb[1024 + n]));
        sh[n] = (1.f - z) * nn + z * phb[n];
    }
    __syncthreads();
    if (tid < 176) {                        // 22 outputs x 8 lanes
        int j = tid >> 3, l = tid & 7;
        float s = 0.f;
        for (int k = l; k < 512; k += 8) s = fmaf(sh[k], Wq[k * 22 + j], s);
        s += __shfl_down(s, 4, 64);
        s += __shfl_down(s, 2, 64);
        s += __shfl_down(s, 1, 64);
        if (l == 0) out[(int64_t)b * 22 + j] = s + bq[j];
    }
}

extern "C" void kernel_launch(void* const* d_in, const int* in_sizes, int n_in,
                              void* d_out, int out_size, void* d_ws, size_t ws_size,
                              hipStream_t stream)
{
    const float* own    = (const float*)d_in[0];
    const float* ally   = (const float*)d_in[1];
    const float* enemy  = (const float*)d_in[2];
    const float* prev_h = (const float*)d_in[3];
    const float* W_own  = (const float*)d_in[4];
    const float* b_own  = (const float*)d_in[5];
    const float* W_ally = (const float*)d_in[6];
    const float* b_ally = (const float*)d_in[7];
    const float* W_enemy= (const float*)d_in[8];
    const float* b_enemy= (const float*)d_in[9];
    const float* Wq_a   = (const float*)d_in[10];
    const float* Wk_a   = (const float*)d_in[11];
    const float* Wv_a   = (const float*)d_in[12];
    const float* Wo_a   = (const float*)d_in[13];
    const float* Wq_e   = (const float*)d_in[14];
    const float* Wk_e   = (const float*)d_in[15];
    const float* Wv_e   = (const float*)d_in[16];
    const float* Wo_e   = (const float*)d_in[17];
    const float* W_ih   = (const float*)d_in[18];
    const float* W_hh   = (const float*)d_in[19];
    const float* b_ih   = (const float*)d_in[20];
    const float* b_hh   = (const float*)d_in[21];
    const float* W_q    = (const float*)d_in[22];
    const float* b_q    = (const float*)d_in[23];
    float* outq = (float*)d_out;
    (void)n_in; (void)out_size;

    const int B = in_sizes[0] / 96;   // 8192

    float* w = (float*)d_ws;
    size_t o = 0;
    auto alloc = [&](size_t n) { float* p = w + o; o += (n + 3) & ~(size_t)3; return p; };
    float* Fq_a   = alloc(96 * 512);
    float* Fq_e   = alloc(96 * 512);
    float* FkA    = alloc(92 * 512);     // rows 0..87 data, row 88 = bkA
    float* FkE    = alloc(92 * 512);     // rows 0..79 data, row 80 = bkE
    float* FvA    = alloc(88 * 512);
    float* FvE    = alloc(80 * 512);
    float* Mm_a   = alloc(8 * 92 * 96);  // adjacent to Mm_e (Z=16 batch)
    float* Mm_e   = alloc(8 * 92 * 96);
    float* b2a    = alloc(736);          // adjacent to b2e (Z=16 batch)
    float* b2e    = alloc(736);
    float* fb     = alloc(6 * 512);
    float* bias_gi= alloc(1536);
    float* WcatT  = alloc(1536 * 1536);
    bf16_t* UTb   = (bf16_t*)alloc(1536 * 1440 / 2);           // bf16
    bf16_t* WhhB  = (bf16_t*)alloc(1536 * 512 / 2);            // bf16
    bf16_t* A_cat = (bf16_t*)alloc((size_t)B * 1440 / 2);      // bf16
    float*  big1  = alloc((size_t)B * 1536 / 2);               // Kq bf16 | gi bf16
    bf16_t* gh    = (bf16_t*)alloc((size_t)B * 1536 / 2);      // bf16
    bf16_t* Kq    = (bf16_t*)big1;       // 16*B*92 bf16 = 24.1 MB
    bf16_t* gi    = (bf16_t*)big1;       // aliases dead Kq (after attn_mid)
    bf16_t* prevhB= A_cat;               // aliases dead A_cat (after gi GEMM)

    if (ws_size < o * sizeof(float)) return;   // clean fail, not a fault

    // ---------------- precompute ----------------
    hipLaunchKernelGGL(f2bf_copy, dim3((1536 * 512 / 4 + 255) / 256), dim3(256), 0, stream,
                       W_hh, WhhB, 1536 * 512 / 4);
    hipLaunchKernelGGL(bias_fuse, dim3(6, 8), dim3(64), 0, stream,
                       b_own, b_ally, b_enemy, Wq_a, Wq_e, Wk_a, Wv_a, Wk_e, Wv_e, fb);
    {
        GemmJobs8 T;
        T.j[0] = { W_own,         Wq_a, Fq_a,          96,   512,  512, 512,  0 };
        T.j[1] = { W_own,         Wq_e, Fq_e,          96,   512,  512, 512,  0 };
        T.j[2] = { W_ally,        Wk_a, FkA,           88,   512,  512, 512,  0 };
        T.j[3] = { W_enemy,       Wk_e, FkE,           80,   512,  512, 512,  0 };
        T.j[4] = { W_ally,        Wv_a, FvA,           88,   512,  512, 512,  0 };
        T.j[5] = { W_enemy,       Wv_e, FvE,           80,   512,  512, 512,  0 };
        T.j[6] = { W_ih + 512,    Wo_a, WcatT + 512,   1536, 1536, 512, 1536, 1 };
        T.j[7] = { W_ih + 1024,   Wo_e, WcatT + 1024,  1536, 1536, 512, 1536, 1 };
        hipLaunchKernelGGL(gemm_multi, dim3(12, 4, 8), dim3(256), 0, stream, T, 512, 512);
    }
    hipLaunchKernelGGL(copy_wih_left, dim3(768), dim3(256), 0, stream, W_ih, WcatT);
    hipLaunchKernelGGL(fkbias_k, dim3(2), dim3(256), 0, stream, fb, FkA, FkE);
    hipLaunchKernelGGL(bias2_k, dim3(6), dim3(256), 0, stream, fb, FkA, FkE, b2a, b2e);
    // Mm[h,c,cc] = sum_d Fk[c,h64+d] * Fq[cc,h64+d]
    hipLaunchKernelGGL((gemm_nt<float>), dim3(1, 1, 8), dim3(256), 0, stream,
                       FkA, 512, (int64_t)64, Fq_a, 512, (int64_t)64,
                       Mm_a, 96, (int64_t)92 * 96, (const float*)nullptr, 0, 92, 96, 64);
    hipLaunchKernelGGL((gemm_nt<float>), dim3(1, 1, 8), dim3(256), 0, stream,
                       FkE, 512, (int64_t)64, Fq_e, 512, (int64_t)64,
                       Mm_e, 96, (int64_t)92 * 96, (const float*)nullptr, 0, 92, 96, 64);
    hipLaunchKernelGGL(bias_gi_k, dim3(6), dim3(256), 0, stream, b_ih, b_own, fb, WcatT, bias_gi);
    // UT (bf16): [:,0:96] own path; [:,96:800] ally-V; [:,800:1440] enemy-V
    hipLaunchKernelGGL((gemm_nt<bf16_t>), dim3(12, 1, 1), dim3(256), 0, stream,
                       WcatT, 1536, (int64_t)0, W_own, 512, (int64_t)0,
                       UTb, 1440, (int64_t)0, (const float*)nullptr, 0, 1536, 96, 512);
    hipLaunchKernelGGL((gemm_nt<bf16_t>), dim3(12, 1, 8), dim3(256), 0, stream,
                       WcatT + 512, 1536, (int64_t)64, FvA, 512, (int64_t)64,
                       UTb + 96, 1440, (int64_t)88, (const float*)nullptr, 0, 1536, 88, 64);
    hipLaunchKernelGGL((gemm_nt<bf16_t>), dim3(12, 1, 8), dim3(256), 0, stream,
                       WcatT + 1024, 1536, (int64_t)64, FvE, 512, (int64_t)64,
                       UTb + 800, 1440, (int64_t)80, (const float*)nullptr, 0, 1536, 80, 64);

    // ---------------- main pipeline ----------------
    // Kq (bf16, 16 slices: z<8 ally heads, z>=8 enemy heads)
    hipLaunchKernelGGL((gemm_nt<bf16_t>), dim3((B + 127) / 128, 1, 16), dim3(256), 0, stream,
                       own, 96, (int64_t)0, Mm_a, 96, (int64_t)92 * 96,
                       Kq, 92, (int64_t)B * 92, b2a, 92, B, 92, 96);
    hipLaunchKernelGGL((attn_mid<15, 88, 96, true>), dim3(B), dim3(128), 0, stream,
                       ally, Kq, own, A_cat, B);
    hipLaunchKernelGGL((attn_mid<16, 80, 800, false>), dim3(B), dim3(128), 0, stream,
                       enemy, Kq + (size_t)8 * B * 92, own, A_cat, B);

    // gi = A_cat @ UTb^T + bias_gi   (MFMA)
    hipLaunchKernelGGL(mfma_nt, dim3(B / 128, 12), dim3(256), 0, stream,
                       A_cat, 1440, UTb, 1440, gi, 1536, bias_gi, 1440);
    // prev_h -> bf16 (aliases dead A_cat), then gh = prevhB @ WhhB^T + b_hh
    hipLaunchKernelGGL(f2bf_copy, dim3((B * 512 / 4 + 255) / 256), dim3(256), 0, stream,
                       prev_h, prevhB, B * 512 / 4);
    hipLaunchKernelGGL(mfma_nt, dim3(B / 128, 12), dim3(256), 0, stream,
                       prevhB, 512, WhhB, 512, gh, 1536, b_hh, 512);

    hipLaunchKernelGGL(gru_final, dim3(B), dim3(256), 0, stream,
                       gi, gh, prev_h, W_q, b_q, outq, B);
}

// Round 4
// 495.570 us; speedup vs baseline: 3.8832x; 1.5638x over previous
//
#include <hip/hip_runtime.h>
#include <cstdint>

// ---------------------------------------------------------------------------
// MHA_QAgent round 4: everything matmul-shaped on MFMA bf16 (job-table
// multi-GEMM for weight folds / Kq / head), GRU fused into the gi GEMM
// epilogue, LDS chunk-XOR swizzle on all MFMA staging.  ~82 MB workspace.
//   Kq[h,b,c]  = ownB[b,:]·Mm[h,c,:] + b2[h,c]       (MFMA, 8 heads/side)
//   A_cat[b,:] = [own(96) | wA 8x88 | wE 8x80] bf16
//   h          = GRU(A_cat@UT^T + bias_gi, gh, prev_h)  (fused epilogue)
//   q          = h @ W_q + b_q                        (MFMA job, f32 out)
// ---------------------------------------------------------------------------

typedef unsigned short bf16_t;
typedef __attribute__((ext_vector_type(8))) short bf16x8;
typedef __attribute__((ext_vector_type(4))) float f32x4;

__device__ inline float bf2f(bf16_t v) { return __uint_as_float(((unsigned)v) << 16); }
__device__ inline bf16_t f2bf(float x) {
    unsigned u = __float_as_uint(x);
    u += 0x7fffu + ((u >> 16) & 1u);          // RNE
    return (bf16_t)(u >> 16);
}
__device__ inline void gload16(const bf16_t* g, bf16_t* l) {
    __builtin_amdgcn_global_load_lds(
        (const __attribute__((address_space(1))) void*)g,
        (__attribute__((address_space(3))) void*)l, 16, 0, 0);
}
__device__ inline int imin(int a, int b) { return a < b ? a : b; }

// ---------------- bf16 convert kernels ----------------
struct CJob { const float* s; bf16_t* d; int n4; };
template <int NJ> struct CJobs { CJob j[NJ]; };

template <int NJ>
__global__ __launch_bounds__(256)
void cvt_plain(CJobs<NJ> T)
{
    CJob jb = T.j[blockIdx.y];
    int stride = gridDim.x * 256;
    for (int i = blockIdx.x * 256 + threadIdx.x; i < jb.n4; i += stride) {
        float4 v = ((const float4*)jb.s)[i];
        ushort4 u; u.x = f2bf(v.x); u.y = f2bf(v.y); u.z = f2bf(v.z); u.w = f2bf(v.w);
        ((ushort4*)jb.d)[i] = u;
    }
}

struct TJob { const float* s; bf16_t* d; int R, C; };   // dst[c][r] = src[r][c]
template <int NJ> struct TJobs { TJob j[NJ]; };

template <int NJ>
__global__ __launch_bounds__(256)
void cvt_trans(TJobs<NJ> T)
{
    TJob jb = T.j[blockIdx.z];
    int c0 = blockIdx.x * 32, r0 = blockIdx.y * 32;
    if (c0 >= jb.C || r0 >= jb.R) return;
    __shared__ float t[32][33];
    int tx = threadIdx.x & 31, ty = threadIdx.x >> 5;
    for (int i = ty; i < 32; i += 8) {
        int r = r0 + i, c = c0 + tx;
        t[i][tx] = (r < jb.R && c < jb.C) ? jb.s[(int64_t)r * jb.C + c] : 0.f;
    }
    __syncthreads();
    for (int i = ty; i < 32; i += 8) {
        int c = c0 + i, r = r0 + tx;
        if (c < jb.C && r < jb.R) jb.d[(int64_t)c * jb.R + r] = f2bf(t[tx][i]);
    }
}

// ---------------- MFMA multi-job NT GEMM (64x64 tile) ----------------
// C[i,j] = sum_k A[i,k]*B[j,k] (+bias[j]).  Row-clamped edge loads; LDS
// chunk-XOR swizzle (chunk ^= (row>>1)&3) applied via pre-swizzled global src.
struct MJob { const bf16_t* A; const bf16_t* Bm; const float* bias; bf16_t* C;
              int lda, ldb, ldc, M, N, K, c32; };
template <int NJ> struct MJobs { MJob j[NJ]; };

template <int NJ>
__global__ __launch_bounds__(256)
void mfma_multi(MJobs<NJ> T)
{
    const MJob jb = T.j[blockIdx.z];
    const int m0 = blockIdx.x * 64, n0 = blockIdx.y * 64;
    if (m0 >= jb.M || n0 >= jb.N) return;
    __shared__ bf16_t As[64][32];
    __shared__ bf16_t Bs[64][32];
    const int tid = threadIdx.x;
    const int wv = tid >> 6, lane = tid & 63;
    const int fr = lane & 15, fq = lane >> 4;
    const int wm = (wv & 1) * 32, wn = (wv >> 1) * 32;
    const int lrow = tid >> 2;
    const int sw = ((lrow >> 1) & 3) ^ (tid & 3);
    const int ar = imin(m0 + lrow, jb.M - 1);
    const int br = imin(n0 + lrow, jb.N - 1);
    const bf16_t* gA = jb.A + (int64_t)ar * jb.lda + sw * 8;
    const bf16_t* gB = jb.Bm + (int64_t)br * jb.ldb + sw * 8;
    bf16_t* lA = &As[wv * 16][0];
    bf16_t* lB = &Bs[wv * 16][0];
    f32x4 acc[2][2] = {};
    for (int k0 = 0; k0 < jb.K; k0 += 32) {
        gload16(gA, lA);
        gload16(gB, lB);
        gA += 32; gB += 32;
        __syncthreads();
        bf16x8 aF[2], bF[2];
#pragma unroll
        for (int i = 0; i < 2; ++i) {
            int rw = wm + i * 16 + fr;
            aF[i] = *(const bf16x8*)&As[rw][(fq ^ ((rw >> 1) & 3)) * 8];
            int rn = wn + i * 16 + fr;
            bF[i] = *(const bf16x8*)&Bs[rn][(fq ^ ((rn >> 1) & 3)) * 8];
        }
#pragma unroll
        for (int i = 0; i < 2; ++i)
#pragma unroll
            for (int j = 0; j < 2; ++j)
                acc[i][j] = __builtin_amdgcn_mfma_f32_16x16x32_bf16(aF[i], bF[j], acc[i][j], 0, 0, 0);
        __syncthreads();
    }
#pragma unroll
    for (int j = 0; j < 2; ++j) {
        const int col = n0 + wn + j * 16 + fr;
        if (col >= jb.N) continue;
        const float bv = jb.bias ? jb.bias[col] : 0.f;
#pragma unroll
        for (int i = 0; i < 2; ++i) {
            const int rowb = m0 + wm + i * 16 + fq * 4;
#pragma unroll
            for (int r = 0; r < 4; ++r) {
                const int row = rowb + r;
                if (row >= jb.M) continue;
                const float v = acc[i][j][r] + bv;
                if (jb.c32) ((float*)jb.C)[(int64_t)row * jb.ldc + col] = v;
                else jb.C[(int64_t)row * jb.ldc + col] = f2bf(v);
            }
        }
    }
}

// ---------------- MFMA 128x128 NT GEMM (gh) ----------------
__global__ __launch_bounds__(256)
void mfma_nt(const bf16_t* __restrict__ A, int lda,
             const bf16_t* __restrict__ Bm, int ldb,
             bf16_t* __restrict__ C, int ldc,
             const float* __restrict__ bias, int K)
{
    __shared__ bf16_t As[128][32];
    __shared__ bf16_t Bs[128][32];
    const int tid = threadIdx.x;
    const int wv = tid >> 6, lane = tid & 63;
    const int fr = lane & 15, fq = lane >> 4;
    const int m0 = blockIdx.x * 128, n0 = blockIdx.y * 128;
    const int wm = (wv & 1) * 64, wn = (wv >> 1) * 64;
    const int lrow = tid >> 2;
    const int sw = ((lrow >> 1) & 3) ^ (tid & 3);
    f32x4 acc[4][4] = {};
    const bf16_t* gA = A + (int64_t)(m0 + lrow) * lda + sw * 8;
    const bf16_t* gB = Bm + (int64_t)(n0 + lrow) * ldb + sw * 8;
    bf16_t* lA0 = &As[wv * 16][0];
    bf16_t* lA1 = &As[64 + wv * 16][0];
    bf16_t* lB0 = &Bs[wv * 16][0];
    bf16_t* lB1 = &Bs[64 + wv * 16][0];
    const int64_t a64 = (int64_t)64 * lda, b64 = (int64_t)64 * ldb;
    for (int k0 = 0; k0 < K; k0 += 32) {
        gload16(gA, lA0);
        gload16(gA + a64, lA1);
        gload16(gB, lB0);
        gload16(gB + b64, lB1);
        gA += 32; gB += 32;
        __syncthreads();
        bf16x8 aF[4], bF[4];
#pragma unroll
        for (int i = 0; i < 4; ++i) {
            int rw = wm + i * 16 + fr;
            aF[i] = *(const bf16x8*)&As[rw][(fq ^ ((rw >> 1) & 3)) * 8];
            int rn = wn + i * 16 + fr;
            bF[i] = *(const bf16x8*)&Bs[rn][(fq ^ ((rn >> 1) & 3)) * 8];
        }
#pragma unroll
        for (int i = 0; i < 4; ++i)
#pragma unroll
            for (int j = 0; j < 4; ++j)
                acc[i][j] = __builtin_amdgcn_mfma_f32_16x16x32_bf16(aF[i], bF[j], acc[i][j], 0, 0, 0);
        __syncthreads();
    }
#pragma unroll
    for (int j = 0; j < 4; ++j) {
        const int col = n0 + wn + j * 16 + fr;
        const float bv = bias[col];
#pragma unroll
        for (int i = 0; i < 4; ++i) {
            const int row = m0 + wm + i * 16 + fq * 4;
#pragma unroll
            for (int r = 0; r < 4; ++r)
                C[(int64_t)(row + r) * ldc + col] = f2bf(acc[i][j][r] + bv);
        }
    }
}

// ---------------- fused gi-GEMM + GRU epilogue -> h (bf16) ----------------
// Block: 128 rows x 64 gate-cols, 3 panels (r,z,n) at col offsets {0,512,1024}.
__global__ __launch_bounds__(256)
void gru_gemm(const bf16_t* __restrict__ A_cat, const bf16_t* __restrict__ UTb,
              const float* __restrict__ biasgi, const bf16_t* __restrict__ gh,
              const float* __restrict__ prev_h, bf16_t* __restrict__ hB)
{
    __shared__ bf16_t As[128][32];
    __shared__ bf16_t Bs[3][64][32];
    const int tid = threadIdx.x;
    const int wv = tid >> 6, lane = tid & 63;
    const int fr = lane & 15, fq = lane >> 4;
    const int wm = (wv & 1) * 64, wn = (wv >> 1) * 32;
    const int m0 = blockIdx.x * 128, nb = blockIdx.y * 64;
    const int lrow = tid >> 2;
    const int sw = ((lrow >> 1) & 3) ^ (tid & 3);
    const bf16_t* gA = A_cat + (int64_t)(m0 + lrow) * 1440 + sw * 8;
    const bf16_t* gB = UTb + (int64_t)(nb + lrow) * 1440 + sw * 8;
    bf16_t* lA0 = &As[wv * 16][0];
    bf16_t* lA1 = &As[64 + wv * 16][0];
    bf16_t* lB0 = &Bs[0][wv * 16][0];
    bf16_t* lB1 = &Bs[1][wv * 16][0];
    bf16_t* lB2 = &Bs[2][wv * 16][0];
    const int64_t a64 = (int64_t)64 * 1440;
    const int64_t p512 = (int64_t)512 * 1440;
    f32x4 acc[3][4][2] = {};
    for (int k0 = 0; k0 < 1440; k0 += 32) {
        gload16(gA, lA0);
        gload16(gA + a64, lA1);
        gload16(gB, lB0);
        gload16(gB + p512, lB1);
        gload16(gB + 2 * p512, lB2);
        gA += 32; gB += 32;
        __syncthreads();
        bf16x8 aF[4], bF[3][2];
#pragma unroll
        for (int i = 0; i < 4; ++i) {
            int rw = wm + i * 16 + fr;
            aF[i] = *(const bf16x8*)&As[rw][(fq ^ ((rw >> 1) & 3)) * 8];
        }
#pragma unroll
        for (int p = 0; p < 3; ++p)
#pragma unroll
            for (int j = 0; j < 2; ++j) {
                int rn = wn + j * 16 + fr;
                bF[p][j] = *(const bf16x8*)&Bs[p][rn][(fq ^ ((rn >> 1) & 3)) * 8];
            }
#pragma unroll
        for (int p = 0; p < 3; ++p)
#pragma unroll
            for (int i = 0; i < 4; ++i)
#pragma unroll
                for (int j = 0; j < 2; ++j)
                    acc[p][i][j] = __builtin_amdgcn_mfma_f32_16x16x32_bf16(aF[i], bF[p][j], acc[p][i][j], 0, 0, 0);
        __syncthreads();
    }
    // GRU epilogue
#pragma unroll
    for (int j = 0; j < 2; ++j) {
        const int col = nb + wn + j * 16 + fr;          // 0..511
        const float bg0 = biasgi[col], bg1 = biasgi[512 + col], bg2 = biasgi[1024 + col];
#pragma unroll
        for (int i = 0; i < 4; ++i) {
            const int rowb = m0 + wm + i * 16 + fq * 4;
#pragma unroll
            for (int r = 0; r < 4; ++r) {
                const int row = rowb + r;
                const bf16_t* g = gh + (int64_t)row * 1536 + col;
                float xr = acc[0][i][j][r] + bg0 + bf2f(g[0]);
                float xz = acc[1][i][j][r] + bg1 + bf2f(g[512]);
                float rr = 1.f / (1.f + expf(-xr));
                float zz = 1.f / (1.f + expf(-xz));
                float xn = acc[2][i][j][r] + bg2 + rr * bf2f(g[1024]);
                float nn = tanhf(xn);
                float hv = (1.f - zz) * nn + zz * prev_h[(int64_t)row * 512 + col];
                hB[(int64_t)row * 512 + col] = f2bf(hv);
            }
        }
    }
}

// ---------------- small kernels ----------------
// fb[job][n] = bvec · W[:,n];  jobs: bqa,bqe,bkA,bvA,bkE,bvE.  4-lane k-split.
__global__ __launch_bounds__(256)
void bias_fuse(const float* __restrict__ b_own, const float* __restrict__ b_ally,
               const float* __restrict__ b_enemy,
               const float* __restrict__ Wq_a, const float* __restrict__ Wq_e,
               const float* __restrict__ Wk_a, const float* __restrict__ Wv_a,
               const float* __restrict__ Wk_e, const float* __restrict__ Wv_e,
               float* __restrict__ fb)
{
    int job = blockIdx.x;
    int n = blockIdx.y * 64 + (threadIdx.x >> 2), q = threadIdx.x & 3;
    const float* v; const float* W;
    switch (job) {
        case 0: v = b_own;   W = Wq_a; break;
        case 1: v = b_own;   W = Wq_e; break;
        case 2: v = b_ally;  W = Wk_a; break;
        case 3: v = b_ally;  W = Wv_a; break;
        case 4: v = b_enemy; W = Wk_e; break;
        default: v = b_enemy; W = Wv_e; break;
    }
    float s = 0.f;
    for (int h = q * 128; h < q * 128 + 128; ++h)
        s = fmaf(v[h], W[(int64_t)h * 512 + n], s);
    s += __shfl_xor(s, 1);
    s += __shfl_xor(s, 2);
    if (q == 0) fb[job * 512 + n] = s;
}

// blk 0..1: FkA/FkE bias row; blk 2..7: bias2 -> b2ab[16][92]; blk 8..31: bias_gi
__global__ __launch_bounds__(256)
void fixups(const float* __restrict__ fb, bf16_t* __restrict__ FkAB, bf16_t* __restrict__ FkEB,
            float* __restrict__ b2ab, const float* __restrict__ b_ih,
            const float* __restrict__ b_own, const float* __restrict__ W_ih,
            const bf16_t* __restrict__ WfaB, const bf16_t* __restrict__ WfeB,
            float* __restrict__ biasgi)
{
    int blk = blockIdx.x, t = threadIdx.x;
    if (blk < 2) {
        int i = blk * 256 + t;            // < 512
        FkAB[88 * 512 + i] = f2bf(fb[2 * 512 + i]);
        FkEB[80 * 512 + i] = f2bf(fb[4 * 512 + i]);
    } else if (blk < 8) {
        int idx = (blk - 2) * 256 + t;
        if (idx < 1472) {
            int side = idx / 736, rem = idx - side * 736;
            int z = rem / 92, c = rem - z * 92;
            const bf16_t* Fk = side ? FkEB : FkAB;
            const float* bq = fb + side * 512;
            const float* bk = fb + (side ? 4 : 2) * 512;
            int BROW = side ? 80 : 88;
            float s = 0.f;
            for (int d = 0; d < 64; ++d) {
                float kv = (c == BROW) ? bk[z * 64 + d] : bf2f(Fk[c * 512 + z * 64 + d]);
                s = fmaf(bq[z * 64 + d], kv, s);
            }
            b2ab[(side * 8 + z) * 92 + c] = s;
        }
    } else {
        int j = (blk - 8) * 64 + (t >> 2), q = t & 3;
        float s = 0.f;
        for (int k = q * 128; k < q * 128 + 128; ++k) {
            s = fmaf(b_own[k],        W_ih[(int64_t)j * 1536 + k], s);
            s = fmaf(fb[3 * 512 + k], bf2f(WfaB[j * 512 + k]), s);
            s = fmaf(fb[5 * 512 + k], bf2f(WfeB[j * 512 + k]), s);
        }
        s += __shfl_xor(s, 1);
        s += __shfl_xor(s, 2);
        if (q == 0) biasgi[j] = s + b_ih[j];
    }
}

// scores from Kq (bf16), mask, softmax, feature re-weighting -> A_cat (bf16).
template <int NENT, int DF, int OFF, bool COPYOWN>
__global__ __launch_bounds__(128)
void attn_mid(const float* __restrict__ ent, const bf16_t* __restrict__ Kq,
              const bf16_t* __restrict__ ownB, bf16_t* __restrict__ acat, int B)
{
    const int b = blockIdx.x, tid = threadIdx.x;
    __shared__ float sent[NENT * DF];
    __shared__ float sKq[8 * (DF + 1)];
    __shared__ float ssc[8][NENT];
    __shared__ int smask[NENT];

    const float* eb = ent + (int64_t)b * NENT * DF;
    for (int i = tid; i < NENT * DF; i += 128) sent[i] = eb[i];
    for (int i = tid; i < 8 * (DF + 1); i += 128) {
        int h = i / (DF + 1), c = i - h * (DF + 1);
        sKq[i] = bf2f(Kq[((int64_t)h * B + b) * 92 + c]);
    }
    __syncthreads();
    if (tid < NENT) {
        int any = 0;
        for (int c = 0; c < DF; ++c) any |= (sent[tid * DF + c] != 0.f);
        smask[tid] = any;
    }
    __syncthreads();
    for (int t = tid; t < 8 * NENT; t += 128) {
        int h = t / NENT, i = t - h * NENT;
        const float* kqh = &sKq[h * (DF + 1)];
        float s = 0.f;
        for (int c = 0; c < DF; ++c) s = fmaf(sent[i * DF + c], kqh[c], s);
        s = (s + kqh[DF]) * 0.125f;
        if (!smask[i]) s = -1e9f;
        ssc[h][i] = s;
    }
    __syncthreads();
    if (tid < 8) {
        float m = -INFINITY;
        for (int i = 0; i < NENT; ++i) m = fmaxf(m, ssc[tid][i]);
        float e[NENT], sum = 0.f;
        for (int i = 0; i < NENT; ++i) { e[i] = expf(ssc[tid][i] - m); sum += e[i]; }
        float inv = 1.f / sum;
        for (int i = 0; i < NENT; ++i) ssc[tid][i] = e[i] * inv;
    }
    __syncthreads();
    bf16_t* arow = acat + (int64_t)b * 1440;
    if (COPYOWN) {
        for (int c = tid; c < 96; c += 128) arow[c] = ownB[(int64_t)b * 96 + c];
    }
    for (int t = tid; t < 8 * DF; t += 128) {
        int h = t / DF, c = t - h * DF;
        float s = 0.f;
        for (int i = 0; i < NENT; ++i) s = fmaf(ssc[h][i], sent[i * DF + c], s);
        arow[OFF + h * DF + c] = f2bf(s);
    }
}

extern "C" void kernel_launch(void* const* d_in, const int* in_sizes, int n_in,
                              void* d_out, int out_size, void* d_ws, size_t ws_size,
                              hipStream_t stream)
{
    const float* own    = (const float*)d_in[0];
    const float* ally   = (const float*)d_in[1];
    const float* enemy  = (const float*)d_in[2];
    const float* prev_h = (const float*)d_in[3];
    const float* W_own  = (const float*)d_in[4];
    const float* b_own  = (const float*)d_in[5];
    const float* W_ally = (const float*)d_in[6];
    const float* b_ally = (const float*)d_in[7];
    const float* W_enemy= (const float*)d_in[8];
    const float* b_enemy= (const float*)d_in[9];
    const float* Wq_a   = (const float*)d_in[10];
    const float* Wk_a   = (const float*)d_in[11];
    const float* Wv_a   = (const float*)d_in[12];
    const float* Wo_a   = (const float*)d_in[13];
    const float* Wq_e   = (const float*)d_in[14];
    const float* Wk_e   = (const float*)d_in[15];
    const float* Wv_e   = (const float*)d_in[16];
    const float* Wo_e   = (const float*)d_in[17];
    const float* W_ih   = (const float*)d_in[18];
    const float* W_hh   = (const float*)d_in[19];
    const float* b_ih   = (const float*)d_in[20];
    const float* b_hh   = (const float*)d_in[21];
    const float* W_q    = (const float*)d_in[22];
    const float* b_q    = (const float*)d_in[23];
    float* outq = (float*)d_out;
    (void)n_in; (void)out_size;

    const int B = in_sizes[0] / 96;   // 8192

    float* w = (float*)d_ws;
    size_t o = 0;
    auto alloc = [&](size_t n) { float* p = w + o; o += (n + 3) & ~(size_t)3; return p; };
    // --- alias block: dead after stage B; prevhB overlays it later ---
    bf16_t* WqT[6];
    for (int i = 0; i < 6; ++i) WqT[i] = (bf16_t*)alloc(131072);
    bf16_t* WoaB  = (bf16_t*)alloc(131072);
    bf16_t* WoeB  = (bf16_t*)alloc(131072);
    bf16_t* WihB  = (bf16_t*)alloc(1179648);
    bf16_t* prevhB= (bf16_t*)w;                     // overlay (needs 2,097,152 f < 2,228,224 f)
    // --- persistent ---
    bf16_t* WhhB  = (bf16_t*)alloc(393216);
    bf16_t* WownB = (bf16_t*)alloc(24576);
    bf16_t* WallyB= (bf16_t*)alloc(22528);
    bf16_t* WenemyB=(bf16_t*)alloc(20480);
    bf16_t* ownB  = (bf16_t*)alloc(393216);
    bf16_t* FqaB  = (bf16_t*)alloc(24576);
    bf16_t* FqeB  = (bf16_t*)alloc(24576);
    bf16_t* FkAB  = (bf16_t*)alloc(23552);          // 92 rows x 512 (row 88 = bkA)
    bf16_t* FkEB  = (bf16_t*)alloc(23552);          // (row 80 = bkE)
    bf16_t* FvAB  = (bf16_t*)alloc(22528);
    bf16_t* FvEB  = (bf16_t*)alloc(20480);
    bf16_t* WfaB  = (bf16_t*)alloc(393216);
    bf16_t* WfeB  = (bf16_t*)alloc(393216);
    bf16_t* MmB   = (bf16_t*)alloc(70656);          // [16][92][96]
    float*  b2ab  = alloc(1472);                    // [16][92]
    float*  fb    = alloc(3072);
    float*  biasgi= alloc(1536);
    bf16_t* WqTq  = (bf16_t*)alloc(5632);           // [22][512]
    bf16_t* UTb   = (bf16_t*)alloc(1105920);        // [1536][1440]
    bf16_t* A_cat = (bf16_t*)alloc((size_t)B * 1440 / 2);
    bf16_t* Kq    = (bf16_t*)alloc((size_t)8 * B * 92 / 2);   // one side at a time
    bf16_t* hB    = Kq;                              // overlays dead Kq
    bf16_t* ghB   = (bf16_t*)alloc((size_t)B * 1536 / 2);

    if (ws_size < o * sizeof(float)) return;        // clean fail, not a fault

    // ---- K1: plain converts ----
    {
        CJobs<8> T;
        T.j[0] = { W_ih,    WihB,    589824 };
        T.j[1] = { W_hh,    WhhB,    196608 };
        T.j[2] = { Wo_a,    WoaB,     65536 };
        T.j[3] = { Wo_e,    WoeB,     65536 };
        T.j[4] = { W_own,   WownB,    12288 };
        T.j[5] = { W_ally,  WallyB,   11264 };
        T.j[6] = { W_enemy, WenemyB,  10240 };
        T.j[7] = { own,     ownB,    196608 };
        hipLaunchKernelGGL((cvt_plain<8>), dim3(128, 8), dim3(256), 0, stream, T);
    }
    // ---- K2: transpose converts ----
    {
        TJobs<7> T;
        T.j[0] = { Wq_a, WqT[0], 512, 512 };
        T.j[1] = { Wq_e, WqT[1], 512, 512 };
        T.j[2] = { Wk_a, WqT[2], 512, 512 };
        T.j[3] = { Wk_e, WqT[3], 512, 512 };
        T.j[4] = { Wv_a, WqT[4], 512, 512 };
        T.j[5] = { Wv_e, WqT[5], 512, 512 };
        T.j[6] = { W_q,  WqTq,   512,  22 };
        hipLaunchKernelGGL((cvt_trans<7>), dim3(16, 16, 7), dim3(256), 0, stream, T);
    }
    // ---- K3: fused biases ----
    hipLaunchKernelGGL(bias_fuse, dim3(6, 8), dim3(256), 0, stream,
                       b_own, b_ally, b_enemy, Wq_a, Wq_e, Wk_a, Wv_a, Wk_e, Wv_e, fb);
    // ---- K4: stage A weight folds ----
    {
        MJobs<8> T;
        T.j[0] = { WownB,        WqT[0], nullptr, FqaB, 512, 512, 512,   96, 512, 512, 0 };
        T.j[1] = { WownB,        WqT[1], nullptr, FqeB, 512, 512, 512,   96, 512, 512, 0 };
        T.j[2] = { WallyB,       WqT[2], nullptr, FkAB, 512, 512, 512,   88, 512, 512, 0 };
        T.j[3] = { WenemyB,      WqT[3], nullptr, FkEB, 512, 512, 512,   80, 512, 512, 0 };
        T.j[4] = { WallyB,       WqT[4], nullptr, FvAB, 512, 512, 512,   88, 512, 512, 0 };
        T.j[5] = { WenemyB,      WqT[5], nullptr, FvEB, 512, 512, 512,   80, 512, 512, 0 };
        T.j[6] = { WihB + 512,   WoaB,   nullptr, WfaB, 1536, 512, 512, 1536, 512, 512, 0 };
        T.j[7] = { WihB + 1024,  WoeB,   nullptr, WfeB, 1536, 512, 512, 1536, 512, 512, 0 };
        hipLaunchKernelGGL((mfma_multi<8>), dim3(24, 8, 8), dim3(256), 0, stream, T);
    }
    // ---- K5: fixups (bias rows, bias2, bias_gi) ----
    hipLaunchKernelGGL(fixups, dim3(32), dim3(256), 0, stream,
                       fb, FkAB, FkEB, b2ab, b_ih, b_own, W_ih, WfaB, WfeB, biasgi);
    // ---- K6: stage B (Mm per head, UT panels) ----
    {
        MJobs<33> T;
        for (int h = 0; h < 8; ++h) {
            T.j[h]     = { FkAB + h * 64, FqaB + h * 64, nullptr, MmB + h * 92 * 96,
                           512, 512, 96, 92, 96, 64, 0 };
            T.j[8 + h] = { FkEB + h * 64, FqeB + h * 64, nullptr, MmB + (8 + h) * 92 * 96,
                           512, 512, 96, 92, 96, 64, 0 };
        }
        T.j[16] = { WihB, WownB, nullptr, UTb, 1536, 512, 1440, 1536, 96, 512, 0 };
        for (int h = 0; h < 8; ++h) {
            T.j[17 + h] = { WfaB + h * 64, FvAB + h * 64, nullptr, UTb + 96 + h * 88,
                            512, 512, 1440, 1536, 88, 64, 0 };
            T.j[25 + h] = { WfeB + h * 64, FvEB + h * 64, nullptr, UTb + 800 + h * 80,
                            512, 512, 1440, 1536, 80, 64, 0 };
        }
        hipLaunchKernelGGL((mfma_multi<33>), dim3(24, 2, 33), dim3(256), 0, stream, T);
    }
    // ---- K7a/K8a: Kq + attention, ally ----
    {
        MJobs<8> T;
        for (int h = 0; h < 8; ++h)
            T.j[h] = { ownB, MmB + h * 92 * 96, b2ab + h * 92, Kq + (size_t)h * B * 92,
                       96, 96, 92, B, 92, 96, 0 };
        hipLaunchKernelGGL((mfma_multi<8>), dim3(B / 64, 2, 8), dim3(256), 0, stream, T);
    }
    hipLaunchKernelGGL((attn_mid<15, 88, 96, true>), dim3(B), dim3(128), 0, stream,
                       ally, Kq, ownB, A_cat, B);
    // ---- K7b/K8b: Kq + attention, enemy (Kq region reused) ----
    {
        MJobs<8> T;
        for (int h = 0; h < 8; ++h)
            T.j[h] = { ownB, MmB + (8 + h) * 92 * 96, b2ab + (8 + h) * 92, Kq + (size_t)h * B * 92,
                       96, 96, 92, B, 92, 96, 0 };
        hipLaunchKernelGGL((mfma_multi<8>), dim3(B / 64, 2, 8), dim3(256), 0, stream, T);
    }
    hipLaunchKernelGGL((attn_mid<16, 80, 800, false>), dim3(B), dim3(128), 0, stream,
                       enemy, Kq, ownB, A_cat, B);
    // ---- K1b: prev_h -> bf16 (overlays dead weight block) ----
    {
        CJobs<1> T;
        T.j[0] = { prev_h, prevhB, B * 512 / 4 };
        hipLaunchKernelGGL((cvt_plain<1>), dim3(512, 1), dim3(256), 0, stream, T);
    }
    // ---- K10: gh = prev_h @ W_hh^T + b_hh ----
    hipLaunchKernelGGL(mfma_nt, dim3(B / 128, 12), dim3(256), 0, stream,
                       prevhB, 512, WhhB, 512, ghB, 1536, b_hh, 512);
    // ---- K9: fused gi GEMM + GRU -> h ----
    hipLaunchKernelGGL(gru_gemm, dim3(B / 128, 8), dim3(256), 0, stream,
                       A_cat, UTb, biasgi, ghB, prev_h, hB);
    // ---- K11: q = h @ W_q + b_q (f32 out) ----
    {
        MJobs<1> T;
        T.j[0] = { hB, WqTq, b_q, (bf16_t*)outq, 512, 512, 22, B, 22, 512, 1 };
        hipLaunchKernelGGL((mfma_multi<1>), dim3(B / 64, 1, 1), dim3(256), 0, stream, T);
    }
}

// Round 5
// 450.954 us; speedup vs baseline: 4.2674x; 1.0989x over previous
//
#include <hip/hip_runtime.h>
#include <cstdint>

// ---------------------------------------------------------------------------
// MHA_QAgent round 5: revert GRU fusion (bad geometry, 214 TF) -> plain
// 128^2 MFMA GEMMs for gi/gh + elementwise GRU+head pass.  Dead-pool overlay
// keeps workspace at 81.6 MB.
//   Kq[h,b,c]  = ownB[b,:]·Mm[h,c,:] + b2[h,c]       (MFMA, 8 heads/side)
//   A_cat[b,:] = [own(96) | wA 8x88 | wE 8x80] bf16
//   gi = A_cat@UT^T + bias_gi   (mfma_nt, K=1440, grid 64x12)
//   gh = prev_h@W_hh^T + b_hh   (mfma_nt, K=512)
//   out = head(GRU(gi, gh, prev_h)) @ W_q + b_q      (gru_final)
// ---------------------------------------------------------------------------

typedef unsigned short bf16_t;
typedef __attribute__((ext_vector_type(8))) short bf16x8;
typedef __attribute__((ext_vector_type(4))) float f32x4;

__device__ inline float bf2f(bf16_t v) { return __uint_as_float(((unsigned)v) << 16); }
__device__ inline bf16_t f2bf(float x) {
    unsigned u = __float_as_uint(x);
    u += 0x7fffu + ((u >> 16) & 1u);          // RNE
    return (bf16_t)(u >> 16);
}
__device__ inline void gload16(const bf16_t* g, bf16_t* l) {
    __builtin_amdgcn_global_load_lds(
        (const __attribute__((address_space(1))) void*)g,
        (__attribute__((address_space(3))) void*)l, 16, 0, 0);
}
__device__ inline int imin(int a, int b) { return a < b ? a : b; }

// ---------------- bf16 convert kernels ----------------
struct CJob { const float* s; bf16_t* d; int n4; };
template <int NJ> struct CJobs { CJob j[NJ]; };

template <int NJ>
__global__ __launch_bounds__(256)
void cvt_plain(CJobs<NJ> T)
{
    CJob jb = T.j[blockIdx.y];
    int stride = gridDim.x * 256;
    for (int i = blockIdx.x * 256 + threadIdx.x; i < jb.n4; i += stride) {
        float4 v = ((const float4*)jb.s)[i];
        ushort4 u; u.x = f2bf(v.x); u.y = f2bf(v.y); u.z = f2bf(v.z); u.w = f2bf(v.w);
        ((ushort4*)jb.d)[i] = u;
    }
}

struct TJob { const float* s; bf16_t* d; int R, C; };   // dst[c][r] = src[r][c]
template <int NJ> struct TJobs { TJob j[NJ]; };

template <int NJ>
__global__ __launch_bounds__(256)
void cvt_trans(TJobs<NJ> T)
{
    TJob jb = T.j[blockIdx.z];
    int c0 = blockIdx.x * 32, r0 = blockIdx.y * 32;
    if (c0 >= jb.C || r0 >= jb.R) return;
    __shared__ float t[32][33];
    int tx = threadIdx.x & 31, ty = threadIdx.x >> 5;
    for (int i = ty; i < 32; i += 8) {
        int r = r0 + i, c = c0 + tx;
        t[i][tx] = (r < jb.R && c < jb.C) ? jb.s[(int64_t)r * jb.C + c] : 0.f;
    }
    __syncthreads();
    for (int i = ty; i < 32; i += 8) {
        int c = c0 + i, r = r0 + tx;
        if (c < jb.C && r < jb.R) jb.d[(int64_t)c * jb.R + r] = f2bf(t[tx][i]);
    }
}

// ---------------- MFMA multi-job NT GEMM (64x64 tile) ----------------
struct MJob { const bf16_t* A; const bf16_t* Bm; const float* bias; bf16_t* C;
              int lda, ldb, ldc, M, N, K, c32; };
template <int NJ> struct MJobs { MJob j[NJ]; };

template <int NJ>
__global__ __launch_bounds__(256)
void mfma_multi(MJobs<NJ> T)
{
    const MJob jb = T.j[blockIdx.z];
    const int m0 = blockIdx.x * 64, n0 = blockIdx.y * 64;
    if (m0 >= jb.M || n0 >= jb.N) return;
    __shared__ bf16_t As[64][32];
    __shared__ bf16_t Bs[64][32];
    const int tid = threadIdx.x;
    const int wv = tid >> 6, lane = tid & 63;
    const int fr = lane & 15, fq = lane >> 4;
    const int wm = (wv & 1) * 32, wn = (wv >> 1) * 32;
    const int lrow = tid >> 2;
    const int sw = ((lrow >> 1) & 3) ^ (tid & 3);
    const int ar = imin(m0 + lrow, jb.M - 1);
    const int br = imin(n0 + lrow, jb.N - 1);
    const bf16_t* gA = jb.A + (int64_t)ar * jb.lda + sw * 8;
    const bf16_t* gB = jb.Bm + (int64_t)br * jb.ldb + sw * 8;
    bf16_t* lA = &As[wv * 16][0];
    bf16_t* lB = &Bs[wv * 16][0];
    f32x4 acc[2][2] = {};
    for (int k0 = 0; k0 < jb.K; k0 += 32) {
        gload16(gA, lA);
        gload16(gB, lB);
        gA += 32; gB += 32;
        __syncthreads();
        bf16x8 aF[2], bF[2];
#pragma unroll
        for (int i = 0; i < 2; ++i) {
            int rw = wm + i * 16 + fr;
            aF[i] = *(const bf16x8*)&As[rw][(fq ^ ((rw >> 1) & 3)) * 8];
            int rn = wn + i * 16 + fr;
            bF[i] = *(const bf16x8*)&Bs[rn][(fq ^ ((rn >> 1) & 3)) * 8];
        }
#pragma unroll
        for (int i = 0; i < 2; ++i)
#pragma unroll
            for (int j = 0; j < 2; ++j)
                acc[i][j] = __builtin_amdgcn_mfma_f32_16x16x32_bf16(aF[i], bF[j], acc[i][j], 0, 0, 0);
        __syncthreads();
    }
#pragma unroll
    for (int j = 0; j < 2; ++j) {
        const int col = n0 + wn + j * 16 + fr;
        if (col >= jb.N) continue;
        const float bv = jb.bias ? jb.bias[col] : 0.f;
#pragma unroll
        for (int i = 0; i < 2; ++i) {
            const int rowb = m0 + wm + i * 16 + fq * 4;
#pragma unroll
            for (int r = 0; r < 4; ++r) {
                const int row = rowb + r;
                if (row >= jb.M) continue;
                const float v = acc[i][j][r] + bv;
                if (jb.c32) ((float*)jb.C)[(int64_t)row * jb.ldc + col] = v;
                else jb.C[(int64_t)row * jb.ldc + col] = f2bf(v);
            }
        }
    }
}

// ---------------- MFMA 128x128 NT GEMM (gi, gh) ----------------
__global__ __launch_bounds__(256)
void mfma_nt(const bf16_t* __restrict__ A, int lda,
             const bf16_t* __restrict__ Bm, int ldb,
             bf16_t* __restrict__ C, int ldc,
             const float* __restrict__ bias, int K)
{
    __shared__ bf16_t As[128][32];
    __shared__ bf16_t Bs[128][32];
    const int tid = threadIdx.x;
    const int wv = tid >> 6, lane = tid & 63;
    const int fr = lane & 15, fq = lane >> 4;
    const int m0 = blockIdx.x * 128, n0 = blockIdx.y * 128;
    const int wm = (wv & 1) * 64, wn = (wv >> 1) * 64;
    const int lrow = tid >> 2;
    const int sw = ((lrow >> 1) & 3) ^ (tid & 3);
    f32x4 acc[4][4] = {};
    const bf16_t* gA = A + (int64_t)(m0 + lrow) * lda + sw * 8;
    const bf16_t* gB = Bm + (int64_t)(n0 + lrow) * ldb + sw * 8;
    bf16_t* lA0 = &As[wv * 16][0];
    bf16_t* lA1 = &As[64 + wv * 16][0];
    bf16_t* lB0 = &Bs[wv * 16][0];
    bf16_t* lB1 = &Bs[64 + wv * 16][0];
    const int64_t a64 = (int64_t)64 * lda, b64 = (int64_t)64 * ldb;
    for (int k0 = 0; k0 < K; k0 += 32) {
        gload16(gA, lA0);
        gload16(gA + a64, lA1);
        gload16(gB, lB0);
        gload16(gB + b64, lB1);
        gA += 32; gB += 32;
        __syncthreads();
        bf16x8 aF[4], bF[4];
#pragma unroll
        for (int i = 0; i < 4; ++i) {
            int rw = wm + i * 16 + fr;
            aF[i] = *(const bf16x8*)&As[rw][(fq ^ ((rw >> 1) & 3)) * 8];
            int rn = wn + i * 16 + fr;
            bF[i] = *(const bf16x8*)&Bs[rn][(fq ^ ((rn >> 1) & 3)) * 8];
        }
#pragma unroll
        for (int i = 0; i < 4; ++i)
#pragma unroll
            for (int j = 0; j < 4; ++j)
                acc[i][j] = __builtin_amdgcn_mfma_f32_16x16x32_bf16(aF[i], bF[j], acc[i][j], 0, 0, 0);
        __syncthreads();
    }
#pragma unroll
    for (int j = 0; j < 4; ++j) {
        const int col = n0 + wn + j * 16 + fr;
        const float bv = bias[col];
#pragma unroll
        for (int i = 0; i < 4; ++i) {
            const int row = m0 + wm + i * 16 + fq * 4;
#pragma unroll
            for (int r = 0; r < 4; ++r)
                C[(int64_t)(row + r) * ldc + col] = f2bf(acc[i][j][r] + bv);
        }
    }
}

// ---------------- small kernels ----------------
// fb[job][n] = bvec · W[:,n];  jobs: bqa,bqe,bkA,bvA,bkE,bvE.  4-lane k-split.
__global__ __launch_bounds__(256)
void bias_fuse(const float* __restrict__ b_own, const float* __restrict__ b_ally,
               const float* __restrict__ b_enemy,
               const float* __restrict__ Wq_a, const float* __restrict__ Wq_e,
               const float* __restrict__ Wk_a, const float* __restrict__ Wv_a,
               const float* __restrict__ Wk_e, const float* __restrict__ Wv_e,
               float* __restrict__ fb)
{
    int job = blockIdx.x;
    int n = blockIdx.y * 64 + (threadIdx.x >> 2), q = threadIdx.x & 3;
    const float* v; const float* W;
    switch (job) {
        case 0: v = b_own;   W = Wq_a; break;
        case 1: v = b_own;   W = Wq_e; break;
        case 2: v = b_ally;  W = Wk_a; break;
        case 3: v = b_ally;  W = Wv_a; break;
        case 4: v = b_enemy; W = Wk_e; break;
        default: v = b_enemy; W = Wv_e; break;
    }
    float s = 0.f;
    for (int h = q * 128; h < q * 128 + 128; ++h)
        s = fmaf(v[h], W[(int64_t)h * 512 + n], s);
    s += __shfl_xor(s, 1);
    s += __shfl_xor(s, 2);
    if (q == 0) fb[job * 512 + n] = s;
}

// blk 0..1: FkA/FkE bias row; blk 2..7: bias2 -> b2ab[16][92]; blk 8..31: bias_gi
__global__ __launch_bounds__(256)
void fixups(const float* __restrict__ fb, bf16_t* __restrict__ FkAB, bf16_t* __restrict__ FkEB,
            float* __restrict__ b2ab, const float* __restrict__ b_ih,
            const float* __restrict__ b_own, const float* __restrict__ W_ih,
            const bf16_t* __restrict__ WfaB, const bf16_t* __restrict__ WfeB,
            float* __restrict__ biasgi)
{
    int blk = blockIdx.x, t = threadIdx.x;
    if (blk < 2) {
        int i = blk * 256 + t;            // < 512
        FkAB[88 * 512 + i] = f2bf(fb[2 * 512 + i]);
        FkEB[80 * 512 + i] = f2bf(fb[4 * 512 + i]);
    } else if (blk < 8) {
        int idx = (blk - 2) * 256 + t;
        if (idx < 1472) {
            int side = idx / 736, rem = idx - side * 736;
            int z = rem / 92, c = rem - z * 92;
            const bf16_t* Fk = side ? FkEB : FkAB;
            const float* bq = fb + side * 512;
            const float* bk = fb + (side ? 4 : 2) * 512;
            int BROW = side ? 80 : 88;
            float s = 0.f;
            for (int d = 0; d < 64; ++d) {
                float kv = (c == BROW) ? bk[z * 64 + d] : bf2f(Fk[c * 512 + z * 64 + d]);
                s = fmaf(bq[z * 64 + d], kv, s);
            }
            b2ab[(side * 8 + z) * 92 + c] = s;
        }
    } else {
        int j = (blk - 8) * 64 + (t >> 2), q = t & 3;
        float s = 0.f;
        for (int k = q * 128; k < q * 128 + 128; ++k) {
            s = fmaf(b_own[k],        W_ih[(int64_t)j * 1536 + k], s);
            s = fmaf(fb[3 * 512 + k], bf2f(WfaB[j * 512 + k]), s);
            s = fmaf(fb[5 * 512 + k], bf2f(WfeB[j * 512 + k]), s);
        }
        s += __shfl_xor(s, 1);
        s += __shfl_xor(s, 2);
        if (q == 0) biasgi[j] = s + b_ih[j];
    }
}

// scores from Kq (bf16), mask, softmax, feature re-weighting -> A_cat (bf16).
template <int NENT, int DF, int OFF, bool COPYOWN>
__global__ __launch_bounds__(128)
void attn_mid(const float* __restrict__ ent, const bf16_t* __restrict__ Kq,
              const bf16_t* __restrict__ ownB, bf16_t* __restrict__ acat, int B)
{
    const int b = blockIdx.x, tid = threadIdx.x;
    __shared__ float sent[NENT * DF];
    __shared__ float sKq[8 * (DF + 1)];
    __shared__ float ssc[8][NENT];
    __shared__ int smask[NENT];

    const float* eb = ent + (int64_t)b * NENT * DF;
    for (int i = tid; i < NENT * DF; i += 128) sent[i] = eb[i];
    for (int i = tid; i < 8 * (DF + 1); i += 128) {
        int h = i / (DF + 1), c = i - h * (DF + 1);
        sKq[i] = bf2f(Kq[((int64_t)h * B + b) * 92 + c]);
    }
    __syncthreads();
    if (tid < NENT) {
        int any = 0;
        for (int c = 0; c < DF; ++c) any |= (sent[tid * DF + c] != 0.f);
        smask[tid] = any;
    }
    __syncthreads();
    for (int t = tid; t < 8 * NENT; t += 128) {
        int h = t / NENT, i = t - h * NENT;
        const float* kqh = &sKq[h * (DF + 1)];
        float s = 0.f;
        for (int c = 0; c < DF; ++c) s = fmaf(sent[i * DF + c], kqh[c], s);
        s = (s + kqh[DF]) * 0.125f;
        if (!smask[i]) s = -1e9f;
        ssc[h][i] = s;
    }
    __syncthreads();
    if (tid < 8) {
        float m = -INFINITY;
        for (int i = 0; i < NENT; ++i) m = fmaxf(m, ssc[tid][i]);
        float e[NENT], sum = 0.f;
        for (int i = 0; i < NENT; ++i) { e[i] = expf(ssc[tid][i] - m); sum += e[i]; }
        float inv = 1.f / sum;
        for (int i = 0; i < NENT; ++i) ssc[tid][i] = e[i] * inv;
    }
    __syncthreads();
    bf16_t* arow = acat + (int64_t)b * 1440;
    if (COPYOWN) {
        for (int c = tid; c < 96; c += 128) arow[c] = ownB[(int64_t)b * 96 + c];
    }
    for (int t = tid; t < 8 * DF; t += 128) {
        int h = t / DF, c = t - h * DF;
        float s = 0.f;
        for (int i = 0; i < NENT; ++i) s = fmaf(ssc[h][i], sent[i * DF + c], s);
        arow[OFF + h * DF + c] = f2bf(s);
    }
}

// GRU combine + 512->22 head (bf16 weights), writes q directly.
__global__ __launch_bounds__(256)
void gru_final(const bf16_t* __restrict__ gi, const bf16_t* __restrict__ gh,
               const float* __restrict__ ph, const bf16_t* __restrict__ Wq,
               const float* __restrict__ bq, float* __restrict__ out, int B)
{
    const int b = blockIdx.x, tid = threadIdx.x;
    __shared__ float sh[512];
    const bf16_t* gib = gi + (int64_t)b * 1536;
    const bf16_t* ghb = gh + (int64_t)b * 1536;
    const float* phb = ph + (int64_t)b * 512;
    for (int n = tid; n < 512; n += 256) {
        float r = 1.f / (1.f + expf(-(bf2f(gib[n]) + bf2f(ghb[n]))));
        float z = 1.f / (1.f + expf(-(bf2f(gib[512 + n]) + bf2f(ghb[512 + n]))));
        float nn = tanhf(bf2f(gib[1024 + n]) + r * bf2f(ghb[1024 + n]));
        sh[n] = (1.f - z) * nn + z * phb[n];
    }
    __syncthreads();
    if (tid < 176) {                        // 22 outputs x 8 lanes
        int j = tid >> 3, l = tid & 7;
        float s = 0.f;
        for (int k = l; k < 512; k += 8) s = fmaf(sh[k], bf2f(Wq[j * 512 + k]), s);
        s += __shfl_down(s, 4, 64);
        s += __shfl_down(s, 2, 64);
        s += __shfl_down(s, 1, 64);
        if (l == 0) out[(int64_t)b * 22 + j] = s + bq[j];
    }
}

extern "C" void kernel_launch(void* const* d_in, const int* in_sizes, int n_in,
                              void* d_out, int out_size, void* d_ws, size_t ws_size,
                              hipStream_t stream)
{
    const float* own    = (const float*)d_in[0];
    const float* ally   = (const float*)d_in[1];
    const float* enemy  = (const float*)d_in[2];
    const float* prev_h = (const float*)d_in[3];
    const float* W_own  = (const float*)d_in[4];
    const float* b_own  = (const float*)d_in[5];
    const float* W_ally = (const float*)d_in[6];
    const float* b_ally = (const float*)d_in[7];
    const float* W_enemy= (const float*)d_in[8];
    const float* b_enemy= (const float*)d_in[9];
    const float* Wq_a   = (const float*)d_in[10];
    const float* Wk_a   = (const float*)d_in[11];
    const float* Wv_a   = (const float*)d_in[12];
    const float* Wo_a   = (const float*)d_in[13];
    const float* Wq_e   = (const float*)d_in[14];
    const float* Wk_e   = (const float*)d_in[15];
    const float* Wv_e   = (const float*)d_in[16];
    const float* Wo_e   = (const float*)d_in[17];
    const float* W_ih   = (const float*)d_in[18];
    const float* W_hh   = (const float*)d_in[19];
    const float* b_ih   = (const float*)d_in[20];
    const float* b_hh   = (const float*)d_in[21];
    const float* W_q    = (const float*)d_in[22];
    const float* b_q    = (const float*)d_in[23];
    float* outq = (float*)d_out;
    (void)n_in; (void)out_size;

    const int B = in_sizes[0] / 96;   // 8192

    float* w = (float*)d_ws;
    size_t o = 0;
    auto alloc = [&](size_t n) { float* p = w + o; o += (n + 3) & ~(size_t)3; return p; };
    // ======== DEAD POOL (everything here is dead before the gi GEMM) ========
    bf16_t* WqT[6];
    for (int i = 0; i < 6; ++i) WqT[i] = (bf16_t*)alloc(131072);
    bf16_t* WoaB  = (bf16_t*)alloc(131072);
    bf16_t* WoeB  = (bf16_t*)alloc(131072);
    bf16_t* WihB  = (bf16_t*)alloc(1179648);
    bf16_t* WhhB  = (bf16_t*)alloc(393216);         // dead after gh GEMM
    bf16_t* WownB = (bf16_t*)alloc(24576);
    bf16_t* WallyB= (bf16_t*)alloc(22528);
    bf16_t* WenemyB=(bf16_t*)alloc(20480);
    bf16_t* ownB  = (bf16_t*)alloc(393216);         // dead after attn enemy
    bf16_t* FqaB  = (bf16_t*)alloc(24576);
    bf16_t* FqeB  = (bf16_t*)alloc(24576);
    bf16_t* FkAB  = (bf16_t*)alloc(23552);          // row 88 = bkA
    bf16_t* FkEB  = (bf16_t*)alloc(23552);          // row 80 = bkE
    bf16_t* FvAB  = (bf16_t*)alloc(22528);
    bf16_t* FvEB  = (bf16_t*)alloc(20480);
    bf16_t* WfaB  = (bf16_t*)alloc(393216);
    bf16_t* WfeB  = (bf16_t*)alloc(393216);
    bf16_t* MmB   = (bf16_t*)alloc(70656);          // [16][92][96]
    float*  b2ab  = alloc(1472);                    // [16][92]
    float*  fb    = alloc(3072);
    bf16_t* Kq    = (bf16_t*)alloc((size_t)8 * B * 92 / 2);   // dead after attn
    // pool end; overlays:
    bf16_t* prevhB= (bf16_t*)w;                     // B*512 bf16 = 2,097,152 f (< WqT..WihB span)
    bf16_t* gi    = (bf16_t*)w;                     // B*1536 bf16 = 6,291,456 f (< pool size)
    if (o < (size_t)B * 1536 / 2) return;           // pool must fit gi (it does: ~7.10M f)
    // ======== LIVE-LATE ========
    float*  biasgi= alloc(1536);
    bf16_t* WqTq  = (bf16_t*)alloc(5632);           // [22][512]
    bf16_t* UTb   = (bf16_t*)alloc(1105920);        // [1536][1440]
    bf16_t* A_cat = (bf16_t*)alloc((size_t)B * 1440 / 2);
    bf16_t* ghB   = (bf16_t*)alloc((size_t)B * 1536 / 2);

    if (ws_size < o * sizeof(float)) return;        // clean fail, not a fault

    // ---- K1: plain converts ----
    {
        CJobs<8> T;
        T.j[0] = { W_ih,    WihB,    589824 };
        T.j[1] = { W_hh,    WhhB,    196608 };
        T.j[2] = { Wo_a,    WoaB,     65536 };
        T.j[3] = { Wo_e,    WoeB,     65536 };
        T.j[4] = { W_own,   WownB,    12288 };
        T.j[5] = { W_ally,  WallyB,   11264 };
        T.j[6] = { W_enemy, WenemyB,  10240 };
        T.j[7] = { own,     ownB,    196608 };
        hipLaunchKernelGGL((cvt_plain<8>), dim3(128, 8), dim3(256), 0, stream, T);
    }
    // ---- K2: transpose converts ----
    {
        TJobs<7> T;
        T.j[0] = { Wq_a, WqT[0], 512, 512 };
        T.j[1] = { Wq_e, WqT[1], 512, 512 };
        T.j[2] = { Wk_a, WqT[2], 512, 512 };
        T.j[3] = { Wk_e, WqT[3], 512, 512 };
        T.j[4] = { Wv_a, WqT[4], 512, 512 };
        T.j[5] = { Wv_e, WqT[5], 512, 512 };
        T.j[6] = { W_q,  WqTq,   512,  22 };
        hipLaunchKernelGGL((cvt_trans<7>), dim3(16, 16, 7), dim3(256), 0, stream, T);
    }
    // ---- K3: fused biases ----
    hipLaunchKernelGGL(bias_fuse, dim3(6, 8), dim3(256), 0, stream,
                       b_own, b_ally, b_enemy, Wq_a, Wq_e, Wk_a, Wv_a, Wk_e, Wv_e, fb);
    // ---- K4: stage A weight folds ----
    {
        MJobs<8> T;
        T.j[0] = { WownB,        WqT[0], nullptr, FqaB, 512, 512, 512,   96, 512, 512, 0 };
        T.j[1] = { WownB,        WqT[1], nullptr, FqeB, 512, 512, 512,   96, 512, 512, 0 };
        T.j[2] = { WallyB,       WqT[2], nullptr, FkAB, 512, 512, 512,   88, 512, 512, 0 };
        T.j[3] = { WenemyB,      WqT[3], nullptr, FkEB, 512, 512, 512,   80, 512, 512, 0 };
        T.j[4] = { WallyB,       WqT[4], nullptr, FvAB, 512, 512, 512,   88, 512, 512, 0 };
        T.j[5] = { WenemyB,      WqT[5], nullptr, FvEB, 512, 512, 512,   80, 512, 512, 0 };
        T.j[6] = { WihB + 512,   WoaB,   nullptr, WfaB, 1536, 512, 512, 1536, 512, 512, 0 };
        T.j[7] = { WihB + 1024,  WoeB,   nullptr, WfeB, 1536, 512, 512, 1536, 512, 512, 0 };
        hipLaunchKernelGGL((mfma_multi<8>), dim3(24, 8, 8), dim3(256), 0, stream, T);
    }
    // ---- K5: fixups (bias rows, bias2, bias_gi) ----
    hipLaunchKernelGGL(fixups, dim3(32), dim3(256), 0, stream,
                       fb, FkAB, FkEB, b2ab, b_ih, b_own, W_ih, WfaB, WfeB, biasgi);
    // ---- K6: stage B (Mm per head, UT panels) ----
    {
        MJobs<33> T;
        for (int h = 0; h < 8; ++h) {
            T.j[h]     = { FkAB + h * 64, FqaB + h * 64, nullptr, MmB + h * 92 * 96,
                           512, 512, 96, 92, 96, 64, 0 };
            T.j[8 + h] = { FkEB + h * 64, FqeB + h * 64, nullptr, MmB + (8 + h) * 92 * 96,
                           512, 512, 96, 92, 96, 64, 0 };
        }
        T.j[16] = { WihB, WownB, nullptr, UTb, 1536, 512, 1440, 1536, 96, 512, 0 };
        for (int h = 0; h < 8; ++h) {
            T.j[17 + h] = { WfaB + h * 64, FvAB + h * 64, nullptr, UTb + 96 + h * 88,
                            512, 512, 1440, 1536, 88, 64, 0 };
            T.j[25 + h] = { WfeB + h * 64, FvEB + h * 64, nullptr, UTb + 800 + h * 80,
                            512, 512, 1440, 1536, 80, 64, 0 };
        }
        hipLaunchKernelGGL((mfma_multi<33>), dim3(24, 2, 33), dim3(256), 0, stream, T);
    }
    // ---- K7: prev_h -> bf16 (overlays WqT..WihB, all dead after K6) ----
    {
        CJobs<1> T;
        T.j[0] = { prev_h, prevhB, B * 512 / 4 };
        hipLaunchKernelGGL((cvt_plain<1>), dim3(512, 1), dim3(256), 0, stream, T);
    }
    // ---- K8: gh = prev_h @ W_hh^T + b_hh  (before attn so prevhB/WhhB die early)
    hipLaunchKernelGGL(mfma_nt, dim3(B / 128, 12), dim3(256), 0, stream,
                       prevhB, 512, WhhB, 512, ghB, 1536, b_hh, 512);
    // ---- K9a/K10a: Kq + attention, ally ----
    {
        MJobs<8> T;
        for (int h = 0; h < 8; ++h)
            T.j[h] = { ownB, MmB + h * 92 * 96, b2ab + h * 92, Kq + (size_t)h * B * 92,
                       96, 96, 92, B, 92, 96, 0 };
        hipLaunchKernelGGL((mfma_multi<8>), dim3(B / 64, 2, 8), dim3(256), 0, stream, T);
    }
    hipLaunchKernelGGL((attn_mid<15, 88, 96, true>), dim3(B), dim3(128), 0, stream,
                       ally, Kq, ownB, A_cat, B);
    // ---- K9b/K10b: Kq + attention, enemy (Kq region reused) ----
    {
        MJobs<8> T;
        for (int h = 0; h < 8; ++h)
            T.j[h] = { ownB, MmB + (8 + h) * 92 * 96, b2ab + (8 + h) * 92, Kq + (size_t)h * B * 92,
                       96, 96, 92, B, 92, 96, 0 };
        hipLaunchKernelGGL((mfma_multi<8>), dim3(B / 64, 2, 8), dim3(256), 0, stream, T);
    }
    hipLaunchKernelGGL((attn_mid<16, 80, 800, false>), dim3(B), dim3(128), 0, stream,
                       enemy, Kq, ownB, A_cat, B);
    // ---- K11: gi = A_cat @ UT^T + bias_gi  (writes into dead pool) ----
    hipLaunchKernelGGL(mfma_nt, dim3(B / 128, 12), dim3(256), 0, stream,
                       A_cat, 1440, UTb, 1440, gi, 1536, biasgi, 1440);
    // ---- K12: GRU + head -> q ----
    hipLaunchKernelGGL(gru_final, dim3(B), dim3(256), 0, stream,
                       gi, ghB, prev_h, WqTq, b_q, outq, B);
}

// Round 6
// 403.077 us; speedup vs baseline: 4.7743x; 1.1188x over previous
//
#include <hip/hip_runtime.h>
#include <cstdint>

// ---------------------------------------------------------------------------
// MHA_QAgent round 6: attention middle moved onto MFMA (9 mfma/wave), Kq as
// two 128^2-geometry GEMMs over padded MmP[8][96][96].  Everything else as
// round 5 (proven).  ~82 MB workspace.
//   Kq[b][h*96+c] = ownB[b,:]·MmP[h,c,:] + b2f[h*96+c]   (mfma_nt, N=768,K=96)
//   attn_mfma: per-wave 16x16x96 scores MFMA + softmax + 16x96x32 PV MFMA
//   gi = A_cat@UT^T + bias_gi   (mfma_nt, K=1440);  gh = prev_h@W_hh^T + b_hh
//   out = head(GRU(gi, gh, prev_h)) @ W_q + b_q      (gru_final)
// ---------------------------------------------------------------------------

typedef unsigned short bf16_t;
typedef __attribute__((ext_vector_type(8))) short bf16x8;
typedef __attribute__((ext_vector_type(4))) float f32x4;

__device__ inline float bf2f(bf16_t v) { return __uint_as_float(((unsigned)v) << 16); }
__device__ inline bf16_t f2bf(float x) {
    unsigned u = __float_as_uint(x);
    u += 0x7fffu + ((u >> 16) & 1u);          // RNE
    return (bf16_t)(u >> 16);
}
__device__ inline void gload16(const bf16_t* g, bf16_t* l) {
    __builtin_amdgcn_global_load_lds(
        (const __attribute__((address_space(1))) void*)g,
        (__attribute__((address_space(3))) void*)l, 16, 0, 0);
}
__device__ inline int imin(int a, int b) { return a < b ? a : b; }

// ---------------- bf16 convert kernels ----------------
struct CJob { const float* s; bf16_t* d; int n4; };
template <int NJ> struct CJobs { CJob j[NJ]; };

template <int NJ>
__global__ __launch_bounds__(256)
void cvt_plain(CJobs<NJ> T)
{
    CJob jb = T.j[blockIdx.y];
    int stride = gridDim.x * 256;
    for (int i = blockIdx.x * 256 + threadIdx.x; i < jb.n4; i += stride) {
        float4 v = ((const float4*)jb.s)[i];
        ushort4 u; u.x = f2bf(v.x); u.y = f2bf(v.y); u.z = f2bf(v.z); u.w = f2bf(v.w);
        ((ushort4*)jb.d)[i] = u;
    }
}

struct TJob { const float* s; bf16_t* d; int R, C; };   // dst[c][r] = src[r][c]
template <int NJ> struct TJobs { TJob j[NJ]; };

template <int NJ>
__global__ __launch_bounds__(256)
void cvt_trans(TJobs<NJ> T)
{
    TJob jb = T.j[blockIdx.z];
    int c0 = blockIdx.x * 32, r0 = blockIdx.y * 32;
    if (c0 >= jb.C || r0 >= jb.R) return;
    __shared__ float t[32][33];
    int tx = threadIdx.x & 31, ty = threadIdx.x >> 5;
    for (int i = ty; i < 32; i += 8) {
        int r = r0 + i, c = c0 + tx;
        t[i][tx] = (r < jb.R && c < jb.C) ? jb.s[(int64_t)r * jb.C + c] : 0.f;
    }
    __syncthreads();
    for (int i = ty; i < 32; i += 8) {
        int c = c0 + i, r = r0 + tx;
        if (c < jb.C && r < jb.R) jb.d[(int64_t)c * jb.R + r] = f2bf(t[tx][i]);
    }
}

// ---------------- MFMA multi-job NT GEMM (64x64 tile) ----------------
struct MJob { const bf16_t* A; const bf16_t* Bm; const float* bias; bf16_t* C;
              int lda, ldb, ldc, M, N, K, c32; };
template <int NJ> struct MJobs { MJob j[NJ]; };

template <int NJ>
__global__ __launch_bounds__(256)
void mfma_multi(MJobs<NJ> T)
{
    const MJob jb = T.j[blockIdx.z];
    const int m0 = blockIdx.x * 64, n0 = blockIdx.y * 64;
    if (m0 >= jb.M || n0 >= jb.N) return;
    __shared__ bf16_t As[64][32];
    __shared__ bf16_t Bs[64][32];
    const int tid = threadIdx.x;
    const int wv = tid >> 6, lane = tid & 63;
    const int fr = lane & 15, fq = lane >> 4;
    const int wm = (wv & 1) * 32, wn = (wv >> 1) * 32;
    const int lrow = tid >> 2;
    const int sw = ((lrow >> 1) & 3) ^ (tid & 3);
    const int ar = imin(m0 + lrow, jb.M - 1);
    const int br = imin(n0 + lrow, jb.N - 1);
    const bf16_t* gA = jb.A + (int64_t)ar * jb.lda + sw * 8;
    const bf16_t* gB = jb.Bm + (int64_t)br * jb.ldb + sw * 8;
    bf16_t* lA = &As[wv * 16][0];
    bf16_t* lB = &Bs[wv * 16][0];
    f32x4 acc[2][2] = {};
    for (int k0 = 0; k0 < jb.K; k0 += 32) {
        gload16(gA, lA);
        gload16(gB, lB);
        gA += 32; gB += 32;
        __syncthreads();
        bf16x8 aF[2], bF[2];
#pragma unroll
        for (int i = 0; i < 2; ++i) {
            int rw = wm + i * 16 + fr;
            aF[i] = *(const bf16x8*)&As[rw][(fq ^ ((rw >> 1) & 3)) * 8];
            int rn = wn + i * 16 + fr;
            bF[i] = *(const bf16x8*)&Bs[rn][(fq ^ ((rn >> 1) & 3)) * 8];
        }
#pragma unroll
        for (int i = 0; i < 2; ++i)
#pragma unroll
            for (int j = 0; j < 2; ++j)
                acc[i][j] = __builtin_amdgcn_mfma_f32_16x16x32_bf16(aF[i], bF[j], acc[i][j], 0, 0, 0);
        __syncthreads();
    }
#pragma unroll
    for (int j = 0; j < 2; ++j) {
        const int col = n0 + wn + j * 16 + fr;
        if (col >= jb.N) continue;
        const float bv = jb.bias ? jb.bias[col] : 0.f;
#pragma unroll
        for (int i = 0; i < 2; ++i) {
            const int rowb = m0 + wm + i * 16 + fq * 4;
#pragma unroll
            for (int r = 0; r < 4; ++r) {
                const int row = rowb + r;
                if (row >= jb.M) continue;
                const float v = acc[i][j][r] + bv;
                if (jb.c32) ((float*)jb.C)[(int64_t)row * jb.ldc + col] = v;
                else jb.C[(int64_t)row * jb.ldc + col] = f2bf(v);
            }
        }
    }
}

// ---------------- MFMA 128x128 NT GEMM (gi, gh, Kq) ----------------
__global__ __launch_bounds__(256)
void mfma_nt(const bf16_t* __restrict__ A, int lda,
             const bf16_t* __restrict__ Bm, int ldb,
             bf16_t* __restrict__ C, int ldc,
             const float* __restrict__ bias, int K)
{
    __shared__ bf16_t As[128][32];
    __shared__ bf16_t Bs[128][32];
    const int tid = threadIdx.x;
    const int wv = tid >> 6, lane = tid & 63;
    const int fr = lane & 15, fq = lane >> 4;
    const int m0 = blockIdx.x * 128, n0 = blockIdx.y * 128;
    const int wm = (wv & 1) * 64, wn = (wv >> 1) * 64;
    const int lrow = tid >> 2;
    const int sw = ((lrow >> 1) & 3) ^ (tid & 3);
    f32x4 acc[4][4] = {};
    const bf16_t* gA = A + (int64_t)(m0 + lrow) * lda + sw * 8;
    const bf16_t* gB = Bm + (int64_t)(n0 + lrow) * ldb + sw * 8;
    bf16_t* lA0 = &As[wv * 16][0];
    bf16_t* lA1 = &As[64 + wv * 16][0];
    bf16_t* lB0 = &Bs[wv * 16][0];
    bf16_t* lB1 = &Bs[64 + wv * 16][0];
    const int64_t a64 = (int64_t)64 * lda, b64 = (int64_t)64 * ldb;
    for (int k0 = 0; k0 < K; k0 += 32) {
        gload16(gA, lA0);
        gload16(gA + a64, lA1);
        gload16(gB, lB0);
        gload16(gB + b64, lB1);
        gA += 32; gB += 32;
        __syncthreads();
        bf16x8 aF[4], bF[4];
#pragma unroll
        for (int i = 0; i < 4; ++i) {
            int rw = wm + i * 16 + fr;
            aF[i] = *(const bf16x8*)&As[rw][(fq ^ ((rw >> 1) & 3)) * 8];
            int rn = wn + i * 16 + fr;
            bF[i] = *(const bf16x8*)&Bs[rn][(fq ^ ((rn >> 1) & 3)) * 8];
        }
#pragma unroll
        for (int i = 0; i < 4; ++i)
#pragma unroll
            for (int j = 0; j < 4; ++j)
                acc[i][j] = __builtin_amdgcn_mfma_f32_16x16x32_bf16(aF[i], bF[j], acc[i][j], 0, 0, 0);
        __syncthreads();
    }
#pragma unroll
    for (int j = 0; j < 4; ++j) {
        const int col = n0 + wn + j * 16 + fr;
        const float bv = bias[col];
#pragma unroll
        for (int i = 0; i < 4; ++i) {
            const int row = m0 + wm + i * 16 + fq * 4;
#pragma unroll
            for (int r = 0; r < 4; ++r)
                C[(int64_t)(row + r) * ldc + col] = f2bf(acc[i][j][r] + bv);
        }
    }
}

// ---------------- MFMA attention middle: one wave per batch row ----------
// scores S[i,h] = sent[i,:96]·Kq[h,:96]  (3 mfma)  -> softmax over i
// wOut[h,c] = P[h,:]·sentT[c,:]          (6 mfma)  -> A_cat[b][OFF..]
// Pads are inert: sent cols >= DF are zero, h>=8 / i>=16 use zero fragments.
template <int NENT, int DF, int OFF, bool COPYOWN>
__global__ __launch_bounds__(256)
void attn_mfma(const float* __restrict__ ent, const bf16_t* __restrict__ Kq,
               const bf16_t* __restrict__ ownB, bf16_t* __restrict__ acat)
{
    __shared__ bf16_t sent[4][16][104];   // A-layout; reused as out[8][96] later
    __shared__ bf16_t sentT[4][96][24];   // B-layout (col-major, padded)
    __shared__ bf16_t pbuf[4][16][24];    // P in A-layout
    __shared__ float  maskf[4][16];       // additive mask (0 or -1e9)

    const int wv = threadIdx.x >> 6, lane = threadIdx.x & 63;
    const int b = blockIdx.x * 4 + wv;
    const int fr = lane & 15, g = lane >> 4;
    const bf16x8 z8 = {0, 0, 0, 0, 0, 0, 0, 0};

    if (lane < 16) maskf[wv][lane] = -1e9f;
    // ---- stage ent -> sent + sentT (bf16, zero-padded) ----
    const float* eb = ent + (int64_t)b * NENT * DF;
#pragma unroll
    for (int t = 0; t < 3; ++t) {
        int idx = lane + t * 64;              // 192 chunks of 8
        int i = idx / 12, c0 = (idx % 12) * 8;
        float v[8];
        bool data = (i < NENT) && (c0 < DF);
        if (data) {
            float4 a = *(const float4*)(eb + (int64_t)i * DF + c0);
            float4 c = *(const float4*)(eb + (int64_t)i * DF + c0 + 4);
            v[0] = a.x; v[1] = a.y; v[2] = a.z; v[3] = a.w;
            v[4] = c.x; v[5] = c.y; v[6] = c.z; v[7] = c.w;
        } else {
#pragma unroll
            for (int j = 0; j < 8; ++j) v[j] = 0.f;
        }
        bf16x8 pk;
        bool any = false;
#pragma unroll
        for (int j = 0; j < 8; ++j) { pk[j] = (short)f2bf(v[j]); any = any || (v[j] != 0.f); }
        *(bf16x8*)&sent[wv][i][c0] = pk;
#pragma unroll
        for (int j = 0; j < 8; ++j) sentT[wv][c0 + j][i] = (bf16_t)pk[j];
        if (any) maskf[wv][i] = 0.f;          // benign race (same value)
    }
    __syncthreads();

    // ---- scores (3 mfma) + softmax ----
    const bf16_t* kqr = Kq + (size_t)b * 768 + fr * 96;
    const float biash = (fr < 8) ? bf2f(kqr[DF]) : 0.f;
    f32x4 S = {};
#pragma unroll
    for (int m = 0; m < 3; ++m) {
        int kc = m * 32 + g * 8;
        bf16x8 af = *(const bf16x8*)&sent[wv][fr][kc];
        bf16x8 kf = (fr < 8) ? *(const bf16x8*)(kqr + kc) : z8;
        S = __builtin_amdgcn_mfma_f32_16x16x32_bf16(af, kf, S, 0, 0, 0);
    }
    float4 mk = *(const float4*)&maskf[wv][g * 4];
    float s0 = (S[0] + biash) * 0.125f + mk.x;
    float s1 = (S[1] + biash) * 0.125f + mk.y;
    float s2 = (S[2] + biash) * 0.125f + mk.z;
    float s3 = (S[3] + biash) * 0.125f + mk.w;
    float mx = fmaxf(fmaxf(s0, s1), fmaxf(s2, s3));
    mx = fmaxf(mx, __shfl_xor(mx, 16, 64));
    mx = fmaxf(mx, __shfl_xor(mx, 32, 64));
    float e0 = __expf(s0 - mx), e1 = __expf(s1 - mx);
    float e2 = __expf(s2 - mx), e3 = __expf(s3 - mx);
    float sum = e0 + e1 + e2 + e3;
    sum += __shfl_xor(sum, 16, 64);
    sum += __shfl_xor(sum, 32, 64);
    float inv = 1.f / sum;
    ushort4 pu;
    pu.x = f2bf(e0 * inv); pu.y = f2bf(e1 * inv);
    pu.z = f2bf(e2 * inv); pu.w = f2bf(e3 * inv);
    *(ushort4*)&pbuf[wv][fr][g * 4] = pu;     // P[h=fr][i=g*4..+3]
    __syncthreads();

    // ---- PV (6 mfma over c-tiles) ----
    bf16x8 pa = (g < 2) ? *(const bf16x8*)&pbuf[wv][fr][g * 8] : z8;
    f32x4 o[6] = {};
#pragma unroll
    for (int t = 0; t < 6; ++t) {
        bf16x8 bfv = (g < 2) ? *(const bf16x8*)&sentT[wv][t * 16 + fr][g * 8] : z8;
        o[t] = __builtin_amdgcn_mfma_f32_16x16x32_bf16(pa, bfv, o[t], 0, 0, 0);
    }
    bf16_t* ob = &sent[wv][0][0];             // reuse as [8][96] (sent is dead)
    if (g < 2) {
#pragma unroll
        for (int t = 0; t < 6; ++t)
#pragma unroll
            for (int r = 0; r < 4; ++r)
                ob[(g * 4 + r) * 96 + t * 16 + fr] = f2bf(o[t][r]);
    }
    __syncthreads();

    // ---- coalesced store to A_cat ----
    bf16_t* arow = acat + (int64_t)b * 1440;
    if (COPYOWN && lane < 12)
        *(bf16x8*)(arow + lane * 8) = *(const bf16x8*)(ownB + (int64_t)b * 96 + lane * 8);
    constexpr int CH = DF / 8;                // 11 (ally) / 10 (enemy)
    if (lane < 8 * CH) {
        int hh = lane / CH, j = lane % CH;
        *(bf16x8*)(arow + OFF + hh * DF + j * 8) = *(const bf16x8*)&ob[hh * 96 + j * 8];
    }
}

// ---------------- small kernels ----------------
// fb[job][n] = bvec · W[:,n];  jobs: bqa,bqe,bkA,bvA,bkE,bvE.  4-lane k-split.
__global__ __launch_bounds__(256)
void bias_fuse(const float* __restrict__ b_own, const float* __restrict__ b_ally,
               const float* __restrict__ b_enemy,
               const float* __restrict__ Wq_a, const float* __restrict__ Wq_e,
               const float* __restrict__ Wk_a, const float* __restrict__ Wv_a,
               const float* __restrict__ Wk_e, const float* __restrict__ Wv_e,
               float* __restrict__ fb)
{
    int job = blockIdx.x;
    int n = blockIdx.y * 64 + (threadIdx.x >> 2), q = threadIdx.x & 3;
    const float* v; const float* W;
    switch (job) {
        case 0: v = b_own;   W = Wq_a; break;
        case 1: v = b_own;   W = Wq_e; break;
        case 2: v = b_ally;  W = Wk_a; break;
        case 3: v = b_ally;  W = Wv_a; break;
        case 4: v = b_enemy; W = Wk_e; break;
        default: v = b_enemy; W = Wv_e; break;
    }
    float s = 0.f;
    for (int h = q * 128; h < q * 128 + 128; ++h)
        s = fmaf(v[h], W[(int64_t)h * 512 + n], s);
    s += __shfl_xor(s, 1);
    s += __shfl_xor(s, 2);
    if (q == 0) fb[job * 512 + n] = s;
}

// blk 0..1: FkA/FkE bias row; blk 2..7: b2f[2][768]; blk 8..31: bias_gi
__global__ __launch_bounds__(256)
void fixups(const float* __restrict__ fb, bf16_t* __restrict__ FkAB, bf16_t* __restrict__ FkEB,
            float* __restrict__ b2f, const float* __restrict__ b_ih,
            const float* __restrict__ b_own, const float* __restrict__ W_ih,
            const bf16_t* __restrict__ WfaB, const bf16_t* __restrict__ WfeB,
            float* __restrict__ biasgi)
{
    int blk = blockIdx.x, t = threadIdx.x;
    if (blk < 2) {
        int i = blk * 256 + t;            // < 512
        FkAB[88 * 512 + i] = f2bf(fb[2 * 512 + i]);
        FkEB[80 * 512 + i] = f2bf(fb[4 * 512 + i]);
    } else if (blk < 8) {
        int idx = (blk - 2) * 256 + t;    // 0..1535 = [side][z*96+c]
        int side = idx / 768, n = idx - side * 768;
        int z = n / 96, c = n - z * 96;
        float s = 0.f;
        if (c < 92) {
            const bf16_t* Fk = side ? FkEB : FkAB;
            const float* bq = fb + side * 512;
            const float* bk = fb + (side ? 4 : 2) * 512;
            int BROW = side ? 80 : 88;
            for (int d = 0; d < 64; ++d) {
                float kv = (c == BROW) ? bk[z * 64 + d] : bf2f(Fk[c * 512 + z * 64 + d]);
                s = fmaf(bq[z * 64 + d], kv, s);
            }
        }
        b2f[idx] = s;
    } else {
        int j = (blk - 8) * 64 + (t >> 2), q = t & 3;
        float s = 0.f;
        for (int k = q * 128; k < q * 128 + 128; ++k) {
            s = fmaf(b_own[k],        W_ih[(int64_t)j * 1536 + k], s);
            s = fmaf(fb[3 * 512 + k], bf2f(WfaB[j * 512 + k]), s);
            s = fmaf(fb[5 * 512 + k], bf2f(WfeB[j * 512 + k]), s);
        }
        s += __shfl_xor(s, 1);
        s += __shfl_xor(s, 2);
        if (q == 0) biasgi[j] = s + b_ih[j];
    }
}

// GRU combine + 512->22 head (bf16 weights), writes q directly.
__global__ __launch_bounds__(256)
void gru_final(const bf16_t* __restrict__ gi, const bf16_t* __restrict__ gh,
               const float* __restrict__ ph, const bf16_t* __restrict__ Wq,
               const float* __restrict__ bq, float* __restrict__ out, int B)
{
    const int b = blockIdx.x, tid = threadIdx.x;
    __shared__ float sh[512];
    const bf16_t* gib = gi + (int64_t)b * 1536;
    const bf16_t* ghb = gh + (int64_t)b * 1536;
    const float* phb = ph + (int64_t)b * 512;
    for (int n = tid; n < 512; n += 256) {
        float r = 1.f / (1.f + expf(-(bf2f(gib[n]) + bf2f(ghb[n]))));
        float z = 1.f / (1.f + expf(-(bf2f(gib[512 + n]) + bf2f(ghb[512 + n]))));
        float nn = tanhf(bf2f(gib[1024 + n]) + r * bf2f(ghb[1024 + n]));
        sh[n] = (1.f - z) * nn + z * phb[n];
    }
    __syncthreads();
    if (tid < 176) {                        // 22 outputs x 8 lanes
        int j = tid >> 3, l = tid & 7;
        float s = 0.f;
        for (int k = l; k < 512; k += 8) s = fmaf(sh[k], bf2f(Wq[j * 512 + k]), s);
        s += __shfl_down(s, 4, 64);
        s += __shfl_down(s, 2, 64);
        s += __shfl_down(s, 1, 64);
        if (l == 0) out[(int64_t)b * 22 + j] = s + bq[j];
    }
}

extern "C" void kernel_launch(void* const* d_in, const int* in_sizes, int n_in,
                              void* d_out, int out_size, void* d_ws, size_t ws_size,
                              hipStream_t stream)
{
    const float* own    = (const float*)d_in[0];
    const float* ally   = (const float*)d_in[1];
    const float* enemy  = (const float*)d_in[2];
    const float* prev_h = (const float*)d_in[3];
    const float* W_own  = (const float*)d_in[4];
    const float* b_own  = (const float*)d_in[5];
    const float* W_ally = (const float*)d_in[6];
    const float* b_ally = (const float*)d_in[7];
    const float* W_enemy= (const float*)d_in[8];
    const float* b_enemy= (const float*)d_in[9];
    const float* Wq_a   = (const float*)d_in[10];
    const float* Wk_a   = (const float*)d_in[11];
    const float* Wv_a   = (const float*)d_in[12];
    const float* Wo_a   = (const float*)d_in[13];
    const float* Wq_e   = (const float*)d_in[14];
    const float* Wk_e   = (const float*)d_in[15];
    const float* Wv_e   = (const float*)d_in[16];
    const float* Wo_e   = (const float*)d_in[17];
    const float* W_ih   = (const float*)d_in[18];
    const float* W_hh   = (const float*)d_in[19];
    const float* b_ih   = (const float*)d_in[20];
    const float* b_hh   = (const float*)d_in[21];
    const float* W_q    = (const float*)d_in[22];
    const float* b_q    = (const float*)d_in[23];
    float* outq = (float*)d_out;
    (void)n_in; (void)out_size;

    const int B = in_sizes[0] / 96;   // 8192

    float* w = (float*)d_ws;
    size_t o = 0;
    auto alloc = [&](size_t n) { float* p = w + o; o += (n + 3) & ~(size_t)3; return p; };
    // ======== DEAD POOL (everything here is dead before the gi GEMM) ========
    bf16_t* WqT[6];
    for (int i = 0; i < 6; ++i) WqT[i] = (bf16_t*)alloc(131072);
    bf16_t* WoaB  = (bf16_t*)alloc(131072);
    bf16_t* WoeB  = (bf16_t*)alloc(131072);
    bf16_t* WihB  = (bf16_t*)alloc(1179648);
    bf16_t* WhhB  = (bf16_t*)alloc(393216);         // dead after gh GEMM
    bf16_t* WownB = (bf16_t*)alloc(24576);
    bf16_t* WallyB= (bf16_t*)alloc(22528);
    bf16_t* WenemyB=(bf16_t*)alloc(20480);
    bf16_t* ownB  = (bf16_t*)alloc(393216);         // dead after attn enemy
    bf16_t* FqaB  = (bf16_t*)alloc(24576);
    bf16_t* FqeB  = (bf16_t*)alloc(24576);
    bf16_t* FkAB  = (bf16_t*)alloc(23552);          // row 88 = bkA
    bf16_t* FkEB  = (bf16_t*)alloc(23552);          // row 80 = bkE
    bf16_t* FvAB  = (bf16_t*)alloc(22528);
    bf16_t* FvEB  = (bf16_t*)alloc(20480);
    bf16_t* WfaB  = (bf16_t*)alloc(393216);
    bf16_t* WfeB  = (bf16_t*)alloc(393216);
    bf16_t* MmPa  = (bf16_t*)alloc(36864);          // [8][96][96]
    bf16_t* MmPe  = (bf16_t*)alloc(36864);
    float*  b2f   = alloc(1536);                    // [2][768]
    float*  fb    = alloc(3072);
    bf16_t* Kq    = (bf16_t*)alloc((size_t)B * 768 / 2);  // [b][768], one side at a time
    // pool end; overlays:
    bf16_t* prevhB= (bf16_t*)w;                     // B*512 bf16 = 2,097,152 f (< WqT..WihB span)
    bf16_t* gi    = (bf16_t*)w;                     // B*1536 bf16 = 6,291,456 f (< pool size)
    if (o < (size_t)B * 1536 / 2) return;           // pool must fit gi
    // ======== LIVE-LATE ========
    float*  biasgi= alloc(1536);
    bf16_t* WqTq  = (bf16_t*)alloc(5632);           // [22][512]
    bf16_t* UTb   = (bf16_t*)alloc(1105920);        // [1536][1440]
    bf16_t* A_cat = (bf16_t*)alloc((size_t)B * 1440 / 2);
    bf16_t* ghB   = (bf16_t*)alloc((size_t)B * 1536 / 2);

    if (ws_size < o * sizeof(float)) return;        // clean fail, not a fault

    // ---- K1: plain converts ----
    {
        CJobs<8> T;
        T.j[0] = { W_ih,    WihB,    589824 };
        T.j[1] = { W_hh,    WhhB,    196608 };
        T.j[2] = { Wo_a,    WoaB,     65536 };
        T.j[3] = { Wo_e,    WoeB,     65536 };
        T.j[4] = { W_own,   WownB,    12288 };
        T.j[5] = { W_ally,  WallyB,   11264 };
        T.j[6] = { W_enemy, WenemyB,  10240 };
        T.j[7] = { own,     ownB,    196608 };
        hipLaunchKernelGGL((cvt_plain<8>), dim3(128, 8), dim3(256), 0, stream, T);
    }
    // ---- K2: transpose converts ----
    {
        TJobs<7> T;
        T.j[0] = { Wq_a, WqT[0], 512, 512 };
        T.j[1] = { Wq_e, WqT[1], 512, 512 };
        T.j[2] = { Wk_a, WqT[2], 512, 512 };
        T.j[3] = { Wk_e, WqT[3], 512, 512 };
        T.j[4] = { Wv_a, WqT[4], 512, 512 };
        T.j[5] = { Wv_e, WqT[5], 512, 512 };
        T.j[6] = { W_q,  WqTq,   512,  22 };
        hipLaunchKernelGGL((cvt_trans<7>), dim3(16, 16, 7), dim3(256), 0, stream, T);
    }
    // ---- K3: fused biases ----
    hipLaunchKernelGGL(bias_fuse, dim3(6, 8), dim3(256), 0, stream,
                       b_own, b_ally, b_enemy, Wq_a, Wq_e, Wk_a, Wv_a, Wk_e, Wv_e, fb);
    // ---- K4: stage A weight folds ----
    {
        MJobs<8> T;
        T.j[0] = { WownB,        WqT[0], nullptr, FqaB, 512, 512, 512,   96, 512, 512, 0 };
        T.j[1] = { WownB,        WqT[1], nullptr, FqeB, 512, 512, 512,   96, 512, 512, 0 };
        T.j[2] = { WallyB,       WqT[2], nullptr, FkAB, 512, 512, 512,   88, 512, 512, 0 };
        T.j[3] = { WenemyB,      WqT[3], nullptr, FkEB, 512, 512, 512,   80, 512, 512, 0 };
        T.j[4] = { WallyB,       WqT[4], nullptr, FvAB, 512, 512, 512,   88, 512, 512, 0 };
        T.j[5] = { WenemyB,      WqT[5], nullptr, FvEB, 512, 512, 512,   80, 512, 512, 0 };
        T.j[6] = { WihB + 512,   WoaB,   nullptr, WfaB, 1536, 512, 512, 1536, 512, 512, 0 };
        T.j[7] = { WihB + 1024,  WoeB,   nullptr, WfeB, 1536, 512, 512, 1536, 512, 512, 0 };
        hipLaunchKernelGGL((mfma_multi<8>), dim3(24, 8, 8), dim3(256), 0, stream, T);
    }
    // ---- K5: fixups (bias rows, b2f, bias_gi) ----
    hipLaunchKernelGGL(fixups, dim3(32), dim3(256), 0, stream,
                       fb, FkAB, FkEB, b2f, b_ih, b_own, W_ih, WfaB, WfeB, biasgi);
    // ---- K6: stage B (MmP per head, UT panels) ----
    {
        MJobs<33> T;
        for (int h = 0; h < 8; ++h) {
            T.j[h]     = { FkAB + h * 64, FqaB + h * 64, nullptr, MmPa + h * 9216,
                           512, 512, 96, 92, 96, 64, 0 };
            T.j[8 + h] = { FkEB + h * 64, FqeB + h * 64, nullptr, MmPe + h * 9216,
                           512, 512, 96, 92, 96, 64, 0 };
        }
        T.j[16] = { WihB, WownB, nullptr, UTb, 1536, 512, 1440, 1536, 96, 512, 0 };
        for (int h = 0; h < 8; ++h) {
            T.j[17 + h] = { WfaB + h * 64, FvAB + h * 64, nullptr, UTb + 96 + h * 88,
                            512, 512, 1440, 1536, 88, 64, 0 };
            T.j[25 + h] = { WfeB + h * 64, FvEB + h * 64, nullptr, UTb + 800 + h * 80,
                            512, 512, 1440, 1536, 80, 64, 0 };
        }
        hipLaunchKernelGGL((mfma_multi<33>), dim3(24, 2, 33), dim3(256), 0, stream, T);
    }
    // ---- K7: prev_h -> bf16 (overlays WqT..WihB, all dead after K6) ----
    {
        CJobs<1> T;
        T.j[0] = { prev_h, prevhB, B * 512 / 4 };
        hipLaunchKernelGGL((cvt_plain<1>), dim3(512, 1), dim3(256), 0, stream, T);
    }
    // ---- K8: gh = prev_h @ W_hh^T + b_hh ----
    hipLaunchKernelGGL(mfma_nt, dim3(B / 128, 12), dim3(256), 0, stream,
                       prevhB, 512, WhhB, 512, ghB, 1536, b_hh, 512);
    // ---- K9a/K10a: Kq GEMM + attention, ally ----
    hipLaunchKernelGGL(mfma_nt, dim3(B / 128, 6), dim3(256), 0, stream,
                       ownB, 96, MmPa, 96, Kq, 768, b2f, 96);
    hipLaunchKernelGGL((attn_mfma<15, 88, 96, true>), dim3(B / 4), dim3(256), 0, stream,
                       ally, Kq, ownB, A_cat);
    // ---- K9b/K10b: Kq GEMM + attention, enemy (Kq buffer reused) ----
    hipLaunchKernelGGL(mfma_nt, dim3(B / 128, 6), dim3(256), 0, stream,
                       ownB, 96, MmPe, 96, Kq, 768, b2f + 768, 96);
    hipLaunchKernelGGL((attn_mfma<16, 80, 800, false>), dim3(B / 4), dim3(256), 0, stream,
                       enemy, Kq, ownB, A_cat);
    // ---- K11: gi = A_cat @ UT^T + bias_gi  (writes into dead pool) ----
    hipLaunchKernelGGL(mfma_nt, dim3(B / 128, 12), dim3(256), 0, stream,
                       A_cat, 1440, UTb, 1440, gi, 1536, biasgi, 1440);
    // ---- K12: GRU + head -> q ----
    hipLaunchKernelGGL(gru_final, dim3(B), dim3(256), 0, stream,
                       gi, ghB, prev_h, WqTq, b_q, outq, B);
}

// Round 7
// 381.224 us; speedup vs baseline: 5.0480x; 1.0573x over previous
//
#include <hip/hip_runtime.h>
#include <cstdint>

// ---------------------------------------------------------------------------
// MHA_QAgent round 7: launch-count 14 -> 11 (single prep kernel), coalesced
// LDS-repacked epilogue in mfma_nt (gi/gh/Kq), vectorized gru_final.
//   Kq[b][h*96+c] = ownB[b,:]·MmP[h,c,:] + b2f[h*96+c]   (mfma_nt, N=768,K=96)
//   attn_mfma: per-wave 16x16x96 scores MFMA + softmax + 16x96x32 PV MFMA
//   gi = A_cat@UT^T + bias_gi   (mfma_nt, K=1440);  gh = prev_h@W_hh^T + b_hh
//   out = head(GRU(gi, gh, prev_h)) @ W_q + b_q      (gru_final)
// Workspace 90.5 MB (pool overlay for gi; prevhB dedicated).
// ---------------------------------------------------------------------------

typedef unsigned short bf16_t;
typedef __attribute__((ext_vector_type(8))) short bf16x8;
typedef __attribute__((ext_vector_type(4))) float f32x4;

__device__ inline float bf2f(bf16_t v) { return __uint_as_float(((unsigned)v) << 16); }
__device__ inline float bf2f_lo(unsigned u) { return __uint_as_float(u << 16); }
__device__ inline float bf2f_hi(unsigned u) { return __uint_as_float(u & 0xffff0000u); }
__device__ inline bf16_t f2bf(float x) {
    unsigned u = __float_as_uint(x);
    u += 0x7fffu + ((u >> 16) & 1u);          // RNE
    return (bf16_t)(u >> 16);
}
__device__ inline void gload16(const bf16_t* g, bf16_t* l) {
    __builtin_amdgcn_global_load_lds(
        (const __attribute__((address_space(1))) void*)g,
        (__attribute__((address_space(3))) void*)l, 16, 0, 0);
}
__device__ inline int imin(int a, int b) { return a < b ? a : b; }

// ---------------- prep: all converts + bias_fuse in one launch ----------
struct CJob { const float* s; bf16_t* d; int n4; };
struct TJob { const float* s; bf16_t* d; int R, C; };   // dst[c][r] = src[r][c]
struct PrepArgs {
    CJob cj[9];
    TJob tj[7];
    const float *b_own, *b_ally, *b_enemy;
    const float *Wq_a, *Wq_e, *Wk_a, *Wv_a, *Wk_e, *Wv_e;
    float* fb;
};

__global__ __launch_bounds__(256)
void prep(PrepArgs P)
{
    const int z = blockIdx.z;
    if (z < 9) {                                   // plain f32->bf16 convert
        CJob jb = P.cj[z];
        int flat = blockIdx.y * 16 + blockIdx.x;   // 0..255
        for (int i = flat * 256 + threadIdx.x; i < jb.n4; i += 256 * 256) {
            float4 v = ((const float4*)jb.s)[i];
            ushort4 u; u.x = f2bf(v.x); u.y = f2bf(v.y); u.z = f2bf(v.z); u.w = f2bf(v.w);
            ((ushort4*)jb.d)[i] = u;
        }
    } else if (z < 16) {                           // transpose convert
        TJob jb = P.tj[z - 9];
        int c0 = blockIdx.x * 32, r0 = blockIdx.y * 32;
        if (c0 >= jb.C || r0 >= jb.R) return;
        __shared__ float t[32][33];
        int tx = threadIdx.x & 31, ty = threadIdx.x >> 5;
        for (int i = ty; i < 32; i += 8) {
            int r = r0 + i, c = c0 + tx;
            t[i][tx] = (r < jb.R && c < jb.C) ? jb.s[(int64_t)r * jb.C + c] : 0.f;
        }
        __syncthreads();
        for (int i = ty; i < 32; i += 8) {
            int c = c0 + i, r = r0 + tx;
            if (c < jb.C && r < jb.R) jb.d[(int64_t)c * jb.R + r] = f2bf(t[tx][i]);
        }
    } else {                                       // bias_fuse: fb[job][n]
        int flat = blockIdx.y * 16 + blockIdx.x;
        if (flat >= 48) return;
        int job = flat >> 3;
        int n = (flat & 7) * 64 + (threadIdx.x >> 2), q = threadIdx.x & 3;
        const float* v; const float* W;
        switch (job) {
            case 0: v = P.b_own;   W = P.Wq_a; break;
            case 1: v = P.b_own;   W = P.Wq_e; break;
            case 2: v = P.b_ally;  W = P.Wk_a; break;
            case 3: v = P.b_ally;  W = P.Wv_a; break;
            case 4: v = P.b_enemy; W = P.Wk_e; break;
            default: v = P.b_enemy; W = P.Wv_e; break;
        }
        float s = 0.f;
        for (int h = q * 128; h < q * 128 + 128; ++h)
            s = fmaf(v[h], W[(int64_t)h * 512 + n], s);
        s += __shfl_xor(s, 1);
        s += __shfl_xor(s, 2);
        if (q == 0) P.fb[job * 512 + n] = s;
    }
}

// ---------------- MFMA multi-job NT GEMM (64x64 tile) ----------------
struct MJob { const bf16_t* A; const bf16_t* Bm; const float* bias; bf16_t* C;
              int lda, ldb, ldc, M, N, K, c32; };
template <int NJ> struct MJobs { MJob j[NJ]; };

template <int NJ>
__global__ __launch_bounds__(256)
void mfma_multi(MJobs<NJ> T)
{
    const MJob jb = T.j[blockIdx.z];
    const int m0 = blockIdx.x * 64, n0 = blockIdx.y * 64;
    if (m0 >= jb.M || n0 >= jb.N) return;
    __shared__ bf16_t As[64][32];
    __shared__ bf16_t Bs[64][32];
    const int tid = threadIdx.x;
    const int wv = tid >> 6, lane = tid & 63;
    const int fr = lane & 15, fq = lane >> 4;
    const int wm = (wv & 1) * 32, wn = (wv >> 1) * 32;
    const int lrow = tid >> 2;
    const int sw = ((lrow >> 1) & 3) ^ (tid & 3);
    const int ar = imin(m0 + lrow, jb.M - 1);
    const int br = imin(n0 + lrow, jb.N - 1);
    const bf16_t* gA = jb.A + (int64_t)ar * jb.lda + sw * 8;
    const bf16_t* gB = jb.Bm + (int64_t)br * jb.ldb + sw * 8;
    bf16_t* lA = &As[wv * 16][0];
    bf16_t* lB = &Bs[wv * 16][0];
    f32x4 acc[2][2] = {};
    for (int k0 = 0; k0 < jb.K; k0 += 32) {
        gload16(gA, lA);
        gload16(gB, lB);
        gA += 32; gB += 32;
        __syncthreads();
        bf16x8 aF[2], bF[2];
#pragma unroll
        for (int i = 0; i < 2; ++i) {
            int rw = wm + i * 16 + fr;
            aF[i] = *(const bf16x8*)&As[rw][(fq ^ ((rw >> 1) & 3)) * 8];
            int rn = wn + i * 16 + fr;
            bF[i] = *(const bf16x8*)&Bs[rn][(fq ^ ((rn >> 1) & 3)) * 8];
        }
#pragma unroll
        for (int i = 0; i < 2; ++i)
#pragma unroll
            for (int j = 0; j < 2; ++j)
                acc[i][j] = __builtin_amdgcn_mfma_f32_16x16x32_bf16(aF[i], bF[j], acc[i][j], 0, 0, 0);
        __syncthreads();
    }
#pragma unroll
    for (int j = 0; j < 2; ++j) {
        const int col = n0 + wn + j * 16 + fr;
        if (col >= jb.N) continue;
        const float bv = jb.bias ? jb.bias[col] : 0.f;
#pragma unroll
        for (int i = 0; i < 2; ++i) {
            const int rowb = m0 + wm + i * 16 + fq * 4;
#pragma unroll
            for (int r = 0; r < 4; ++r) {
                const int row = rowb + r;
                if (row >= jb.M) continue;
                const float v = acc[i][j][r] + bv;
                if (jb.c32) ((float*)jb.C)[(int64_t)row * jb.ldc + col] = v;
                else jb.C[(int64_t)row * jb.ldc + col] = f2bf(v);
            }
        }
    }
}

// ---------------- MFMA 128x128 NT GEMM (gi, gh, Kq) ----------------
// LDS-repacked epilogue: acc -> Cs (bf16) -> coalesced bf16x8 stores.
__global__ __launch_bounds__(256)
void mfma_nt(const bf16_t* __restrict__ A, int lda,
             const bf16_t* __restrict__ Bm, int ldb,
             bf16_t* __restrict__ C, int ldc,
             const float* __restrict__ bias, int K)
{
    __shared__ bf16_t As[128][32];
    __shared__ bf16_t Bs[128][32];
    __shared__ bf16_t Cs[128][132];      // +4 pad
    const int tid = threadIdx.x;
    const int wv = tid >> 6, lane = tid & 63;
    const int fr = lane & 15, fq = lane >> 4;
    const int m0 = blockIdx.x * 128, n0 = blockIdx.y * 128;
    const int wm = (wv & 1) * 64, wn = (wv >> 1) * 64;
    const int lrow = tid >> 2;
    const int sw = ((lrow >> 1) & 3) ^ (tid & 3);
    f32x4 acc[4][4] = {};
    const bf16_t* gA = A + (int64_t)(m0 + lrow) * lda + sw * 8;
    const bf16_t* gB = Bm + (int64_t)(n0 + lrow) * ldb + sw * 8;
    bf16_t* lA0 = &As[wv * 16][0];
    bf16_t* lA1 = &As[64 + wv * 16][0];
    bf16_t* lB0 = &Bs[wv * 16][0];
    bf16_t* lB1 = &Bs[64 + wv * 16][0];
    const int64_t a64 = (int64_t)64 * lda, b64 = (int64_t)64 * ldb;
    for (int k0 = 0; k0 < K; k0 += 32) {
        gload16(gA, lA0);
        gload16(gA + a64, lA1);
        gload16(gB, lB0);
        gload16(gB + b64, lB1);
        gA += 32; gB += 32;
        __syncthreads();
        bf16x8 aF[4], bF[4];
#pragma unroll
        for (int i = 0; i < 4; ++i) {
            int rw = wm + i * 16 + fr;
            aF[i] = *(const bf16x8*)&As[rw][(fq ^ ((rw >> 1) & 3)) * 8];
            int rn = wn + i * 16 + fr;
            bF[i] = *(const bf16x8*)&Bs[rn][(fq ^ ((rn >> 1) & 3)) * 8];
        }
#pragma unroll
        for (int i = 0; i < 4; ++i)
#pragma unroll
            for (int j = 0; j < 4; ++j)
                acc[i][j] = __builtin_amdgcn_mfma_f32_16x16x32_bf16(aF[i], bF[j], acc[i][j], 0, 0, 0);
        __syncthreads();
    }
    // epilogue: repack via LDS, coalesced stores
#pragma unroll
    for (int j = 0; j < 4; ++j) {
        const int col = wn + j * 16 + fr;
        const float bv = bias[n0 + col];
#pragma unroll
        for (int i = 0; i < 4; ++i) {
            const int rowb = wm + i * 16 + fq * 4;
#pragma unroll
            for (int r = 0; r < 4; ++r)
                Cs[rowb + r][col] = f2bf(acc[i][j][r] + bv);
        }
    }
    __syncthreads();
    const int srow = tid >> 4, c8 = (tid & 15) * 8;
#pragma unroll
    for (int p = 0; p < 8; ++p) {
        const int row = srow + p * 16;
        *(bf16x8*)(C + (int64_t)(m0 + row) * ldc + n0 + c8) = *(const bf16x8*)&Cs[row][c8];
    }
}

// ---------------- MFMA attention middle: one wave per batch row ----------
template <int NENT, int DF, int OFF, bool COPYOWN>
__global__ __launch_bounds__(256)
void attn_mfma(const float* __restrict__ ent, const bf16_t* __restrict__ Kq,
               const bf16_t* __restrict__ ownB, bf16_t* __restrict__ acat)
{
    __shared__ bf16_t sent[4][16][104];   // A-layout; reused as out[8][96] later
    __shared__ bf16_t sentT[4][96][24];   // B-layout (col-major, padded)
    __shared__ bf16_t pbuf[4][16][24];    // P in A-layout
    __shared__ float  maskf[4][16];       // additive mask (0 or -1e9)

    const int wv = threadIdx.x >> 6, lane = threadIdx.x & 63;
    const int b = blockIdx.x * 4 + wv;
    const int fr = lane & 15, g = lane >> 4;
    const bf16x8 z8 = {0, 0, 0, 0, 0, 0, 0, 0};

    if (lane < 16) maskf[wv][lane] = -1e9f;
    const float* eb = ent + (int64_t)b * NENT * DF;
#pragma unroll
    for (int t = 0; t < 3; ++t) {
        int idx = lane + t * 64;              // 192 chunks of 8
        int i = idx / 12, c0 = (idx % 12) * 8;
        float v[8];
        bool data = (i < NENT) && (c0 < DF);
        if (data) {
            float4 a = *(const float4*)(eb + (int64_t)i * DF + c0);
            float4 c = *(const float4*)(eb + (int64_t)i * DF + c0 + 4);
            v[0] = a.x; v[1] = a.y; v[2] = a.z; v[3] = a.w;
            v[4] = c.x; v[5] = c.y; v[6] = c.z; v[7] = c.w;
        } else {
#pragma unroll
            for (int j = 0; j < 8; ++j) v[j] = 0.f;
        }
        bf16x8 pk;
        bool any = false;
#pragma unroll
        for (int j = 0; j < 8; ++j) { pk[j] = (short)f2bf(v[j]); any = any || (v[j] != 0.f); }
        *(bf16x8*)&sent[wv][i][c0] = pk;
#pragma unroll
        for (int j = 0; j < 8; ++j) sentT[wv][c0 + j][i] = (bf16_t)pk[j];
        if (any) maskf[wv][i] = 0.f;          // benign race (same value)
    }
    __syncthreads();

    const bf16_t* kqr = Kq + (size_t)b * 768 + fr * 96;
    const float biash = (fr < 8) ? bf2f(kqr[DF]) : 0.f;
    f32x4 S = {};
#pragma unroll
    for (int m = 0; m < 3; ++m) {
        int kc = m * 32 + g * 8;
        bf16x8 af = *(const bf16x8*)&sent[wv][fr][kc];
        bf16x8 kf = (fr < 8) ? *(const bf16x8*)(kqr + kc) : z8;
        S = __builtin_amdgcn_mfma_f32_16x16x32_bf16(af, kf, S, 0, 0, 0);
    }
    float4 mk = *(const float4*)&maskf[wv][g * 4];
    float s0 = (S[0] + biash) * 0.125f + mk.x;
    float s1 = (S[1] + biash) * 0.125f + mk.y;
    float s2 = (S[2] + biash) * 0.125f + mk.z;
    float s3 = (S[3] + biash) * 0.125f + mk.w;
    float mx = fmaxf(fmaxf(s0, s1), fmaxf(s2, s3));
    mx = fmaxf(mx, __shfl_xor(mx, 16, 64));
    mx = fmaxf(mx, __shfl_xor(mx, 32, 64));
    float e0 = __expf(s0 - mx), e1 = __expf(s1 - mx);
    float e2 = __expf(s2 - mx), e3 = __expf(s3 - mx);
    float sum = e0 + e1 + e2 + e3;
    sum += __shfl_xor(sum, 16, 64);
    sum += __shfl_xor(sum, 32, 64);
    float inv = 1.f / sum;
    ushort4 pu;
    pu.x = f2bf(e0 * inv); pu.y = f2bf(e1 * inv);
    pu.z = f2bf(e2 * inv); pu.w = f2bf(e3 * inv);
    *(ushort4*)&pbuf[wv][fr][g * 4] = pu;     // P[h=fr][i=g*4..+3]
    __syncthreads();

    bf16x8 pa = (g < 2) ? *(const bf16x8*)&pbuf[wv][fr][g * 8] : z8;
    f32x4 o[6] = {};
#pragma unroll
    for (int t = 0; t < 6; ++t) {
        bf16x8 bfv = (g < 2) ? *(const bf16x8*)&sentT[wv][t * 16 + fr][g * 8] : z8;
        o[t] = __builtin_amdgcn_mfma_f32_16x16x32_bf16(pa, bfv, o[t], 0, 0, 0);
    }
    bf16_t* ob = &sent[wv][0][0];             // reuse as [8][96] (sent is dead)
    if (g < 2) {
#pragma unroll
        for (int t = 0; t < 6; ++t)
#pragma unroll
            for (int r = 0; r < 4; ++r)
                ob[(g * 4 + r) * 96 + t * 16 + fr] = f2bf(o[t][r]);
    }
    __syncthreads();

    bf16_t* arow = acat + (int64_t)b * 1440;
    if (COPYOWN && lane < 12)
        *(bf16x8*)(arow + lane * 8) = *(const bf16x8*)(ownB + (int64_t)b * 96 + lane * 8);
    constexpr int CH = DF / 8;                // 11 (ally) / 10 (enemy)
    if (lane < 8 * CH) {
        int hh = lane / CH, j = lane % CH;
        *(bf16x8*)(arow + OFF + hh * DF + j * 8) = *(const bf16x8*)&ob[hh * 96 + j * 8];
    }
}

// ---------------- fixups ----------------
// blk 0..1: FkA/FkE bias row; blk 2..7: b2f[2][768]; blk 8..31: bias_gi
__global__ __launch_bounds__(256)
void fixups(const float* __restrict__ fb, bf16_t* __restrict__ FkAB, bf16_t* __restrict__ FkEB,
            float* __restrict__ b2f, const float* __restrict__ b_ih,
            const float* __restrict__ b_own, const float* __restrict__ W_ih,
            const bf16_t* __restrict__ WfaB, const bf16_t* __restrict__ WfeB,
            float* __restrict__ biasgi)
{
    int blk = blockIdx.x, t = threadIdx.x;
    if (blk < 2) {
        int i = blk * 256 + t;            // < 512
        FkAB[88 * 512 + i] = f2bf(fb[2 * 512 + i]);
        FkEB[80 * 512 + i] = f2bf(fb[4 * 512 + i]);
    } else if (blk < 8) {
        int idx = (blk - 2) * 256 + t;    // 0..1535 = [side][z*96+c]
        int side = idx / 768, n = idx - side * 768;
        int z = n / 96, c = n - z * 96;
        float s = 0.f;
        if (c < 92) {
            const bf16_t* Fk = side ? FkEB : FkAB;
            const float* bq = fb + side * 512;
            const float* bk = fb + (side ? 4 : 2) * 512;
            int BROW = side ? 80 : 88;
            for (int d = 0; d < 64; ++d) {
                float kv = (c == BROW) ? bk[z * 64 + d] : bf2f(Fk[c * 512 + z * 64 + d]);
                s = fmaf(bq[z * 64 + d], kv, s);
            }
        }
        b2f[idx] = s;
    } else {
        int j = (blk - 8) * 64 + (t >> 2), q = t & 3;
        float s = 0.f;
        for (int k = q * 128; k < q * 128 + 128; ++k) {
            s = fmaf(b_own[k],        W_ih[(int64_t)j * 1536 + k], s);
            s = fmaf(fb[3 * 512 + k], bf2f(WfaB[j * 512 + k]), s);
            s = fmaf(fb[5 * 512 + k], bf2f(WfeB[j * 512 + k]), s);
        }
        s += __shfl_xor(s, 1);
        s += __shfl_xor(s, 2);
        if (q == 0) biasgi[j] = s + b_ih[j];
    }
}

// ---------------- GRU combine + 512->22 head ----------------
__global__ __launch_bounds__(256)
void gru_final(const bf16_t* __restrict__ gi, const bf16_t* __restrict__ gh,
               const float* __restrict__ ph, const bf16_t* __restrict__ Wq,
               const float* __restrict__ bq, float* __restrict__ out, int B)
{
    const int b = blockIdx.x, tid = threadIdx.x;
    __shared__ float sh[512];
    const bf16_t* gib = gi + (int64_t)b * 1536;
    const bf16_t* ghb = gh + (int64_t)b * 1536;
    const float* phb = ph + (int64_t)b * 512;
    {
        const int n = tid * 2;
        unsigned gr = *(const unsigned*)(gib + n);
        unsigned gz = *(const unsigned*)(gib + 512 + n);
        unsigned gn = *(const unsigned*)(gib + 1024 + n);
        unsigned hr = *(const unsigned*)(ghb + n);
        unsigned hz = *(const unsigned*)(ghb + 512 + n);
        unsigned hn = *(const unsigned*)(ghb + 1024 + n);
        float2 p2 = *(const float2*)(phb + n);
        {
            float r = 1.f / (1.f + __expf(-(bf2f_lo(gr) + bf2f_lo(hr))));
            float z = 1.f / (1.f + __expf(-(bf2f_lo(gz) + bf2f_lo(hz))));
            float nn = tanhf(bf2f_lo(gn) + r * bf2f_lo(hn));
            sh[n] = (1.f - z) * nn + z * p2.x;
        }
        {
            float r = 1.f / (1.f + __expf(-(bf2f_hi(gr) + bf2f_hi(hr))));
            float z = 1.f / (1.f + __expf(-(bf2f_hi(gz) + bf2f_hi(hz))));
            float nn = tanhf(bf2f_hi(gn) + r * bf2f_hi(hn));
            sh[n + 1] = (1.f - z) * nn + z * p2.y;
        }
    }
    __syncthreads();
    if (tid < 176) {                        // 22 outputs x 8 lanes
        int j = tid >> 3, l = tid & 7;
        float s = 0.f;
        for (int k = l; k < 512; k += 8) s = fmaf(sh[k], bf2f(Wq[j * 512 + k]), s);
        s += __shfl_down(s, 4, 64);
        s += __shfl_down(s, 2, 64);
        s += __shfl_down(s, 1, 64);
        if (l == 0) out[(int64_t)b * 22 + j] = s + bq[j];
    }
}

extern "C" void kernel_launch(void* const* d_in, const int* in_sizes, int n_in,
                              void* d_out, int out_size, void* d_ws, size_t ws_size,
                              hipStream_t stream)
{
    const float* own    = (const float*)d_in[0];
    const float* ally   = (const float*)d_in[1];
    const float* enemy  = (const float*)d_in[2];
    const float* prev_h = (const float*)d_in[3];
    const float* W_own  = (const float*)d_in[4];
    const float* b_own  = (const float*)d_in[5];
    const float* W_ally = (const float*)d_in[6];
    const float* b_ally = (const float*)d_in[7];
    const float* W_enemy= (const float*)d_in[8];
    const float* b_enemy= (const float*)d_in[9];
    const float* Wq_a   = (const float*)d_in[10];
    const float* Wk_a   = (const float*)d_in[11];
    const float* Wv_a   = (const float*)d_in[12];
    const float* Wo_a   = (const float*)d_in[13];
    const float* Wq_e   = (const float*)d_in[14];
    const float* Wk_e   = (const float*)d_in[15];
    const float* Wv_e   = (const float*)d_in[16];
    const float* Wo_e   = (const float*)d_in[17];
    const float* W_ih   = (const float*)d_in[18];
    const float* W_hh   = (const float*)d_in[19];
    const float* b_ih   = (const float*)d_in[20];
    const float* b_hh   = (const float*)d_in[21];
    const float* W_q    = (const float*)d_in[22];
    const float* b_q    = (const float*)d_in[23];
    float* outq = (float*)d_out;
    (void)n_in; (void)out_size;

    const int B = in_sizes[0] / 96;   // 8192

    float* w = (float*)d_ws;
    size_t o = 0;
    auto alloc = [&](size_t n) { float* p = w + o; o += (n + 3) & ~(size_t)3; return p; };
    // ======== DEAD POOL (everything here is dead before the gi GEMM) ========
    bf16_t* WqT[6];
    for (int i = 0; i < 6; ++i) WqT[i] = (bf16_t*)alloc(131072);
    bf16_t* WoaB  = (bf16_t*)alloc(131072);
    bf16_t* WoeB  = (bf16_t*)alloc(131072);
    bf16_t* WihB  = (bf16_t*)alloc(1179648);
    bf16_t* WhhB  = (bf16_t*)alloc(393216);         // dead after gh GEMM
    bf16_t* WownB = (bf16_t*)alloc(24576);
    bf16_t* WallyB= (bf16_t*)alloc(22528);
    bf16_t* WenemyB=(bf16_t*)alloc(20480);
    bf16_t* ownB  = (bf16_t*)alloc(393216);         // dead after Kq-enemy
    bf16_t* FqaB  = (bf16_t*)alloc(24576);
    bf16_t* FqeB  = (bf16_t*)alloc(24576);
    bf16_t* FkAB  = (bf16_t*)alloc(23552);          // row 88 = bkA
    bf16_t* FkEB  = (bf16_t*)alloc(23552);          // row 80 = bkE
    bf16_t* FvAB  = (bf16_t*)alloc(22528);
    bf16_t* FvEB  = (bf16_t*)alloc(20480);
    bf16_t* WfaB  = (bf16_t*)alloc(393216);
    bf16_t* WfeB  = (bf16_t*)alloc(393216);
    bf16_t* MmPa  = (bf16_t*)alloc(36864);          // [768][96]
    bf16_t* MmPe  = (bf16_t*)alloc(36864);
    float*  b2f   = alloc(1536);                    // [2][768]
    float*  fb    = alloc(3072);
    bf16_t* Kq    = (bf16_t*)alloc((size_t)B * 768 / 2);  // [b][768], one side at a time
    // pool end; overlay:
    bf16_t* gi    = (bf16_t*)w;                     // B*1536 bf16 = 6,291,456 f
    if (o < (size_t)B * 1536 / 2) return;           // pool must fit gi (~7.23M f)
    // ======== LIVE-LATE ========
    float*  biasgi= alloc(1536);
    bf16_t* WqTq  = (bf16_t*)alloc(5632);           // [22][512]
    bf16_t* UTb   = (bf16_t*)alloc(1105920);        // [1536][1440]
    bf16_t* A_cat = (bf16_t*)alloc((size_t)B * 1440 / 2);
    bf16_t* ghB   = (bf16_t*)alloc((size_t)B * 1536 / 2);
    bf16_t* prevhB= (bf16_t*)alloc((size_t)B * 512 / 2);   // dedicated (prep-time)

    if (ws_size < o * sizeof(float)) return;        // clean fail, not a fault

    // ---- L1: prep (all converts + bias_fuse) ----
    {
        PrepArgs P;
        P.cj[0] = { W_ih,    WihB,    589824 };
        P.cj[1] = { W_hh,    WhhB,    196608 };
        P.cj[2] = { Wo_a,    WoaB,     65536 };
        P.cj[3] = { Wo_e,    WoeB,     65536 };
        P.cj[4] = { W_own,   WownB,    12288 };
        P.cj[5] = { W_ally,  WallyB,   11264 };
        P.cj[6] = { W_enemy, WenemyB,  10240 };
        P.cj[7] = { own,     ownB,    196608 };
        P.cj[8] = { prev_h,  prevhB,  B * 512 / 4 };
        P.tj[0] = { Wq_a, WqT[0], 512, 512 };
        P.tj[1] = { Wq_e, WqT[1], 512, 512 };
        P.tj[2] = { Wk_a, WqT[2], 512, 512 };
        P.tj[3] = { Wk_e, WqT[3], 512, 512 };
        P.tj[4] = { Wv_a, WqT[4], 512, 512 };
        P.tj[5] = { Wv_e, WqT[5], 512, 512 };
        P.tj[6] = { W_q,  WqTq,   512,  22 };
        P.b_own = b_own; P.b_ally = b_ally; P.b_enemy = b_enemy;
        P.Wq_a = Wq_a; P.Wq_e = Wq_e; P.Wk_a = Wk_a; P.Wv_a = Wv_a;
        P.Wk_e = Wk_e; P.Wv_e = Wv_e; P.fb = fb;
        hipLaunchKernelGGL(prep, dim3(16, 16, 17), dim3(256), 0, stream, P);
    }
    // ---- L2: gh = prev_h @ W_hh^T + b_hh  (independent of fold chain) ----
    hipLaunchKernelGGL(mfma_nt, dim3(B / 128, 12), dim3(256), 0, stream,
                       prevhB, 512, WhhB, 512, ghB, 1536, b_hh, 512);
    // ---- L3: stage A weight folds ----
    {
        MJobs<8> T;
        T.j[0] = { WownB,        WqT[0], nullptr, FqaB, 512, 512, 512,   96, 512, 512, 0 };
        T.j[1] = { WownB,        WqT[1], nullptr, FqeB, 512, 512, 512,   96, 512, 512, 0 };
        T.j[2] = { WallyB,       WqT[2], nullptr, FkAB, 512, 512, 512,   88, 512, 512, 0 };
        T.j[3] = { WenemyB,      WqT[3], nullptr, FkEB, 512, 512, 512,   80, 512, 512, 0 };
        T.j[4] = { WallyB,       WqT[4], nullptr, FvAB, 512, 512, 512,   88, 512, 512, 0 };
        T.j[5] = { WenemyB,      WqT[5], nullptr, FvEB, 512, 512, 512,   80, 512, 512, 0 };
        T.j[6] = { WihB + 512,   WoaB,   nullptr, WfaB, 1536, 512, 512, 1536, 512, 512, 0 };
        T.j[7] = { WihB + 1024,  WoeB,   nullptr, WfeB, 1536, 512, 512, 1536, 512, 512, 0 };
        hipLaunchKernelGGL((mfma_multi<8>), dim3(24, 8, 8), dim3(256), 0, stream, T);
    }
    // ---- L4: fixups (bias rows, b2f, bias_gi) ----
    hipLaunchKernelGGL(fixups, dim3(32), dim3(256), 0, stream,
                       fb, FkAB, FkEB, b2f, b_ih, b_own, W_ih, WfaB, WfeB, biasgi);
    // ---- L5: stage B (MmP per head, UT panels) ----
    {
        MJobs<33> T;
        for (int h = 0; h < 8; ++h) {
            T.j[h]     = { FkAB + h * 64, FqaB + h * 64, nullptr, MmPa + h * 9216,
                           512, 512, 96, 92, 96, 64, 0 };
            T.j[8 + h] = { FkEB + h * 64, FqeB + h * 64, nullptr, MmPe + h * 9216,
                           512, 512, 96, 92, 96, 64, 0 };
        }
        T.j[16] = { WihB, WownB, nullptr, UTb, 1536, 512, 1440, 1536, 96, 512, 0 };
        for (int h = 0; h < 8; ++h) {
            T.j[17 + h] = { WfaB + h * 64, FvAB + h * 64, nullptr, UTb + 96 + h * 88,
                            512, 512, 1440, 1536, 88, 64, 0 };
            T.j[25 + h] = { WfeB + h * 64, FvEB + h * 64, nullptr, UTb + 800 + h * 80,
                            512, 512, 1440, 1536, 80, 64, 0 };
        }
        hipLaunchKernelGGL((mfma_multi<33>), dim3(24, 2, 33), dim3(256), 0, stream, T);
    }
    // ---- L6/L7: Kq GEMM + attention, ally ----
    hipLaunchKernelGGL(mfma_nt, dim3(B / 128, 6), dim3(256), 0, stream,
                       ownB, 96, MmPa, 96, Kq, 768, b2f, 96);
    hipLaunchKernelGGL((attn_mfma<15, 88, 96, true>), dim3(B / 4), dim3(256), 0, stream,
                       ally, Kq, ownB, A_cat);
    // ---- L8/L9: Kq GEMM + attention, enemy (Kq buffer reused) ----
    hipLaunchKernelGGL(mfma_nt, dim3(B / 128, 6), dim3(256), 0, stream,
                       ownB, 96, MmPe, 96, Kq, 768, b2f + 768, 96);
    hipLaunchKernelGGL((attn_mfma<16, 80, 800, false>), dim3(B / 4), dim3(256), 0, stream,
                       enemy, Kq, ownB, A_cat);
    // ---- L10: gi = A_cat @ UT^T + bias_gi  (writes into dead pool) ----
    hipLaunchKernelGGL(mfma_nt, dim3(B / 128, 12), dim3(256), 0, stream,
                       A_cat, 1440, UTb, 1440, gi, 1536, biasgi, 1440);
    // ---- L11: GRU + head -> q ----
    hipLaunchKernelGGL(gru_final, dim3(B), dim3(256), 0, stream,
                       gi, ghB, prev_h, WqTq, b_q, outq, B);
}